// Round 5
// baseline (785.697 us; speedup 1.0000x reference)
//
#include <hip/hip_runtime.h>

#define N_NODES 25000
#define N_EDGES 400000

// ---------------- fast transcendentals (fp32, ~2ulp) ----------------
__device__ __forceinline__ float fast_sigmoid(float x) {
    return __builtin_amdgcn_rcpf(1.0f + __expf(-x));
}
__device__ __forceinline__ float fast_tanh(float x) {
    return 1.0f - 2.0f * __builtin_amdgcn_rcpf(__expf(2.0f * x) + 1.0f);
}

// lane j receives value from lane j^k within its 32-lane half (k<16 keeps it
// inside the 16-lane node group). BitMode offset = (xor<<10)|(or<<5)|and.
#define SWZF(x, k) __int_as_float(__builtin_amdgcn_ds_swizzle(__float_as_int(x), ((k) << 10) | 0x1F))
// broadcast lane t of each 16-lane group: src = (lane & 0x10) | t
#define BCAST16(x, t) __int_as_float(__builtin_amdgcn_ds_swizzle(__float_as_int(x), ((t) << 5) | 0x10))

// ---------------- K1: hidden0 = nf @ W_init + b_init ; copy; zero cnt/rcnt ---
__global__ void __launch_bounds__(256) k_init(
        const float* __restrict__ nf, const float* __restrict__ Wini,
        const float* __restrict__ bini,
        float* __restrict__ hidden0, float* __restrict__ hid,
        int* __restrict__ cnt, int* __restrict__ rcnt)
{
    int gtid = blockIdx.x * 256 + threadIdx.x;
    if (gtid <= N_NODES) { cnt[gtid] = 0; rcnt[gtid] = 0; }
    int node = gtid >> 4;
    int j = gtid & 15;
    if (node >= N_NODES) return;

    const float4* nf4 = (const float4*)(nf + node * 32);
    float acc = bini[j];
#pragma unroll
    for (int g = 0; g < 8; ++g) {
        float4 v = nf4[g];
        acc = fmaf(v.x, Wini[(g*4+0)*16 + j], acc);
        acc = fmaf(v.y, Wini[(g*4+1)*16 + j], acc);
        acc = fmaf(v.z, Wini[(g*4+2)*16 + j], acc);
        acc = fmaf(v.w, Wini[(g*4+3)*16 + j], acc);
    }
    hidden0[node*16 + j] = acc;
    hid[node*16 + j] = acc;
}

// ---------------- fused CSR builds ----------------
__global__ void __launch_bounds__(256) k_hist2(const int* __restrict__ send,
        const int* __restrict__ recv,
        int* __restrict__ cnt, int* __restrict__ rcnt)
{
    int e = blockIdx.x * 256 + threadIdx.x;
    if (e < N_EDGES) {
        atomicAdd(&cnt[send[e]], 1);
        atomicAdd(&rcnt[recv[e]], 1);
    }
}

// two exclusive scans in one single-block kernel
__global__ void __launch_bounds__(1024) k_scan2(
        const int* __restrict__ cnt,  int* __restrict__ row_ptr,  int* __restrict__ cursor,
        const int* __restrict__ rcnt, int* __restrict__ rrow_ptr, int* __restrict__ rcur,
        float* __restrict__ out)
{
    __shared__ int sums[1024];
    int t = threadIdx.x;
    const int CH = (N_NODES + 1023) / 1024 + 1;   // 25 -> covers 25600

#define SCAN_PASS(SRC, DST0, DST1) { \
        int base = t * CH; \
        int s = 0; \
        for (int i = 0; i < CH; ++i) { \
            int idx = base + i; \
            if (idx < N_NODES) s += SRC[idx]; \
        } \
        sums[t] = s; \
        __syncthreads(); \
        for (int off = 1; off < 1024; off <<= 1) { \
            int add = (t >= off) ? sums[t - off] : 0; \
            __syncthreads(); \
            sums[t] += add; \
            __syncthreads(); \
        } \
        int run = sums[t] - s; \
        for (int i = 0; i < CH; ++i) { \
            int idx = base + i; \
            if (idx < N_NODES) { \
                DST0[idx] = run; \
                DST1[idx] = run; \
                run += SRC[idx]; \
            } \
        } \
        __syncthreads(); }

    SCAN_PASS(cnt, row_ptr, cursor)
    SCAN_PASS(rcnt, rrow_ptr, rcur)
#undef SCAN_PASS

    if (t == 0) {
        row_ptr[N_NODES]  = N_EDGES;
        rrow_ptr[N_NODES] = N_EDGES;
        out[0] = 0.0f;
    }
}

// fused: sender-CSR (eids) + receiver-CSR over sender positions (rpos)
__global__ void __launch_bounds__(256) k_scatter2(const int* __restrict__ send,
        const int* __restrict__ recv,
        int* __restrict__ cursor, int* __restrict__ rcur,
        int* __restrict__ eids, int* __restrict__ rpos)
{
    int e = blockIdx.x * 256 + threadIdx.x;
    if (e < N_EDGES) {
        int pos = atomicAdd(&cursor[send[e]], 1);
        eids[pos] = e;
        int p = atomicAdd(&rcur[recv[e]], 1);
        rpos[p] = pos;
    }
}

// efp[pos,:] = ef[eids[pos],:]  (edge features into sender-CSR order; once)
__global__ void __launch_bounds__(256) k_permute(const float* __restrict__ ef,
        const int* __restrict__ eids, float* __restrict__ efp)
{
    int gtid = blockIdx.x * 256 + threadIdx.x;
    int pos = gtid >> 4;
    int c = gtid & 15;
    if (pos < N_EDGES) efp[(size_t)pos*16 + c] = ef[(size_t)eids[pos]*16 + c];
}

// ---------------- K3: one sender per WAVE, 4 edge-slots, unroll x2 ----------
// lane = (slot = lane>>4, m = lane&15). q[f][m] = sum_h We[f][m*16+h]*h[s][h]
// (computed redundantly per slot; We is L1-resident). Per iteration the wave
// processes 8 edges (2 per slot) -> 8 x 64B lines in flight, 2x256B
// contiguous stores. 25000 waves -> deep backfill pool for latency hiding.
#define MSG16(E0,E1,E2,E3) ( \
    ( fmaf((E0).w,q[3],  fmaf((E0).z,q[2],  fmaf((E0).y,q[1],  fmaf((E0).x,q[0],  qb)))) \
    + fmaf((E1).w,q[7],  fmaf((E1).z,q[6],  fmaf((E1).y,q[5],  fmaf((E1).x,q[4],  0.0f)))) ) \
  + ( fmaf((E2).w,q[11], fmaf((E2).z,q[10], fmaf((E2).y,q[9],  fmaf((E2).x,q[8],  0.0f)))) \
    + fmaf((E3).w,q[15], fmaf((E3).z,q[14], fmaf((E3).y,q[13], fmaf((E3).x,q[12], 0.0f)))) ) )

__global__ void __launch_bounds__(256) k_msg(
        const float* __restrict__ hid, const float* __restrict__ efp,
        const float* __restrict__ We, const float* __restrict__ be,
        const int* __restrict__ row_ptr,
        float* __restrict__ tmp)
{
    int wid  = (blockIdx.x * 256 + threadIdx.x) >> 6;   // wave id = sender
    int lane = threadIdx.x & 63;
    int m    = lane & 15;
    int slot = lane >> 4;                               // 0..3
    if (wid >= N_NODES) return;
    int s = wid;

    float h[16];
    {
        const float4* h4 = (const float4*)(hid + s*16);
        float4 a = h4[0], b = h4[1], c = h4[2], d = h4[3];
        h[0]=a.x; h[1]=a.y; h[2]=a.z;  h[3]=a.w;
        h[4]=b.x; h[5]=b.y; h[6]=b.z;  h[7]=b.w;
        h[8]=c.x; h[9]=c.y; h[10]=c.z; h[11]=c.w;
        h[12]=d.x; h[13]=d.y; h[14]=d.z; h[15]=d.w;
    }
    float q[16];
#pragma unroll
    for (int f = 0; f < 16; ++f) {
        const float4* wf = (const float4*)(We + f*256 + m*16);
        float4 a = wf[0], b = wf[1], c = wf[2], d = wf[3];
        float acc;
        acc  = a.x*h[0]  + a.y*h[1]  + a.z*h[2]  + a.w*h[3];
        acc += b.x*h[4]  + b.y*h[5]  + b.z*h[6]  + b.w*h[7];
        acc += c.x*h[8]  + c.y*h[9]  + c.z*h[10] + c.w*h[11];
        acc += d.x*h[12] + d.y*h[13] + d.z*h[14] + d.w*h[15];
        q[f] = acc;
    }
    float qb;
    {
        const float4* bf = (const float4*)(be + m*16);
        float4 a = bf[0], b = bf[1], c = bf[2], d = bf[3];
        qb  = a.x*h[0]  + a.y*h[1]  + a.z*h[2]  + a.w*h[3];
        qb += b.x*h[4]  + b.y*h[5]  + b.z*h[6]  + b.w*h[7];
        qb += c.x*h[8]  + c.y*h[9]  + c.z*h[10] + c.w*h[11];
        qb += d.x*h[12] + d.y*h[13] + d.z*h[14] + d.w*h[15];
    }

    int beg = row_ptr[s];
    int end = row_ptr[s + 1];
    for (int i = beg; i < end; i += 8) {
        int eA = i + slot;
        int eB = i + 4 + slot;
        bool aA = eA < end;
        bool aB = eB < end;
        const float4* pA = (const float4*)(efp + (size_t)(aA ? eA : beg) * 16);
        const float4* pB = (const float4*)(efp + (size_t)(aB ? eB : beg) * 16);
        float4 A0 = pA[0], A1 = pA[1], A2 = pA[2], A3 = pA[3];
        float4 B0 = pB[0], B1 = pB[1], B2 = pB[2], B3 = pB[3];
        float vA = MSG16(A0, A1, A2, A3);
        float vB = MSG16(B0, B1, B2, B3);
        if (aA) tmp[(size_t)eA*16 + m] = vA;
        if (aB) tmp[(size_t)eB*16 + m] = vB;
    }
}

// ---------------- K4: line-gather + GRU (T=32), 2 scalars/lane ---------------
// 16 lanes per node, lane j = GRU unit j. In-edges listed by rpos (receiver-
// CSR over sender positions): lane j reads ONLY dword j of each 64B message
// line -> group fetches each line exactly once (tmp is L3-resident).
// Gather unrolled x8 with 4 accumulators for MLP.
__global__ void __launch_bounds__(256) k_gru(
        const float* __restrict__ hid_in, const float* __restrict__ tmp,
        const int* __restrict__ rrow_ptr, const int* __restrict__ rpos,
        const float* __restrict__ Wi, const float* __restrict__ Wh,
        const float* __restrict__ bi, const float* __restrict__ bh,
        float* __restrict__ hid_out)
{
    int gtid = blockIdx.x * 256 + threadIdx.x;
    int node = gtid >> 4;
    int j = gtid & 15;
    if (node >= N_NODES) return;

    float s0 = 0.0f, s1 = 0.0f, s2 = 0.0f, s3 = 0.0f;
    {
        int beg = rrow_ptr[node];
        int end = rrow_ptr[node + 1];
        int d = end - beg;
        int i = 0;
        for (; i + 8 <= d; i += 8) {
            int p0 = rpos[beg + i + 0];
            int p1 = rpos[beg + i + 1];
            int p2 = rpos[beg + i + 2];
            int p3 = rpos[beg + i + 3];
            int p4 = rpos[beg + i + 4];
            int p5 = rpos[beg + i + 5];
            int p6 = rpos[beg + i + 6];
            int p7 = rpos[beg + i + 7];
            float a0 = tmp[(size_t)p0*16 + j];
            float a1 = tmp[(size_t)p1*16 + j];
            float a2 = tmp[(size_t)p2*16 + j];
            float a3 = tmp[(size_t)p3*16 + j];
            float a4 = tmp[(size_t)p4*16 + j];
            float a5 = tmp[(size_t)p5*16 + j];
            float a6 = tmp[(size_t)p6*16 + j];
            float a7 = tmp[(size_t)p7*16 + j];
            s0 += a0; s1 += a1; s2 += a2; s3 += a3;
            s0 += a4; s1 += a5; s2 += a6; s3 += a7;
        }
        for (; i < d; ++i) s0 += tmp[(size_t)rpos[beg + i]*16 + j];
    }
    float msg_own = (s0 + s1) + (s2 + s3);
    float h_own = hid_in[node*16 + j];

    float Wz[16], Wr[16], Wc[16];
#pragma unroll
    for (int k = 0; k < 16; ++k) {
        int l = j ^ k;
        Wz[k] = Wh[l*48 + j];
        Wr[k] = Wh[l*48 + 16 + j];
        Wc[k] = Wh[l*48 + 32 + j];
    }
    float Wiz = Wi[j], Wir = Wi[16+j], Wih = Wi[32+j];
    float cz   = bi[j] + bh[j];
    float cr   = bi[16+j] + bh[16+j];
    float bih_ = bi[32+j];
    float bhh_ = bh[32+j];

    float hn = 0.0f;

#define STEPK(k) { float v = SWZF(hn, k); \
        az = fmaf(v, Wz[k], az); ar = fmaf(v, Wr[k], ar); ac = fmaf(v, Wc[k], ac); }

#define GRUSTEP(XV) { \
        float xv = (XV); \
        float az = fmaf(xv, Wiz, cz); \
        float ar = fmaf(xv, Wir, cr); \
        float ac = bhh_; \
        az = fmaf(hn, Wz[0], az); \
        ar = fmaf(hn, Wr[0], ar); \
        ac = fmaf(hn, Wc[0], ac); \
        STEPK(1)  STEPK(2)  STEPK(3)  STEPK(4)  STEPK(5) \
        STEPK(6)  STEPK(7)  STEPK(8)  STEPK(9)  STEPK(10) \
        STEPK(11) STEPK(12) STEPK(13) STEPK(14) STEPK(15) \
        float z  = fast_sigmoid(az); \
        float r  = fast_sigmoid(ar); \
        float hc = fast_tanh(fmaf(xv, Wih, bih_) + r * ac); \
        hn = fmaf(z, hn - hc, hc); }

    // t = 0..15: x_t = hidden[node][t]
    GRUSTEP(BCAST16(h_own, 0))  GRUSTEP(BCAST16(h_own, 1))
    GRUSTEP(BCAST16(h_own, 2))  GRUSTEP(BCAST16(h_own, 3))
    GRUSTEP(BCAST16(h_own, 4))  GRUSTEP(BCAST16(h_own, 5))
    GRUSTEP(BCAST16(h_own, 6))  GRUSTEP(BCAST16(h_own, 7))
    GRUSTEP(BCAST16(h_own, 8))  GRUSTEP(BCAST16(h_own, 9))
    GRUSTEP(BCAST16(h_own, 10)) GRUSTEP(BCAST16(h_own, 11))
    GRUSTEP(BCAST16(h_own, 12)) GRUSTEP(BCAST16(h_own, 13))
    GRUSTEP(BCAST16(h_own, 14)) GRUSTEP(BCAST16(h_own, 15))
    // t = 16..31: x_t = messages[node][t-16]
    GRUSTEP(BCAST16(msg_own, 0))  GRUSTEP(BCAST16(msg_own, 1))
    GRUSTEP(BCAST16(msg_own, 2))  GRUSTEP(BCAST16(msg_own, 3))
    GRUSTEP(BCAST16(msg_own, 4))  GRUSTEP(BCAST16(msg_own, 5))
    GRUSTEP(BCAST16(msg_own, 6))  GRUSTEP(BCAST16(msg_own, 7))
    GRUSTEP(BCAST16(msg_own, 8))  GRUSTEP(BCAST16(msg_own, 9))
    GRUSTEP(BCAST16(msg_own, 10)) GRUSTEP(BCAST16(msg_own, 11))
    GRUSTEP(BCAST16(msg_own, 12)) GRUSTEP(BCAST16(msg_own, 13))
    GRUSTEP(BCAST16(msg_own, 14)) GRUSTEP(BCAST16(msg_own, 15))
#undef GRUSTEP
#undef STEPK

    hid_out[node*16 + j] = hn;
}

// ---------------- K5: readout ----------------
__global__ void __launch_bounds__(256) k_readout(
        const float* __restrict__ hid, const float* __restrict__ hid0,
        const float* __restrict__ Wri, const float* __restrict__ bri,
        const float* __restrict__ Wrj, const float* __restrict__ brj,
        float* __restrict__ out)
{
    int n = blockIdx.x * 256 + threadIdx.x;
    float val = 0.0f;
    if (n < N_NODES) {
        const float4* h4 = (const float4*)(hid + n * 16);
        const float4* g4 = (const float4*)(hid0 + n * 16);
        float iv = bri[0];
        float jv = brj[0];
#pragma unroll
        for (int g = 0; g < 4; ++g) {
            float4 h  = h4[g];
            float4 h0 = g4[g];
            iv = fmaf(h.x,  Wri[g*4+0], iv);  iv = fmaf(h.y,  Wri[g*4+1], iv);
            iv = fmaf(h.z,  Wri[g*4+2], iv);  iv = fmaf(h.w,  Wri[g*4+3], iv);
            iv = fmaf(h0.x, Wri[16+g*4+0], iv); iv = fmaf(h0.y, Wri[16+g*4+1], iv);
            iv = fmaf(h0.z, Wri[16+g*4+2], iv); iv = fmaf(h0.w, Wri[16+g*4+3], iv);
            jv = fmaf(h.x,  Wrj[g*4+0], jv);  jv = fmaf(h.y,  Wrj[g*4+1], jv);
            jv = fmaf(h.z,  Wrj[g*4+2], jv);  jv = fmaf(h.w,  Wrj[g*4+3], jv);
        }
        val = iv * jv;
    }
#pragma unroll
    for (int off = 32; off > 0; off >>= 1)
        val += __shfl_xor(val, off, 64);
    __shared__ float wsum[4];
    int w = threadIdx.x >> 6;
    if ((threadIdx.x & 63) == 0) wsum[w] = val;
    __syncthreads();
    if (threadIdx.x == 0)
        atomicAdd(out, wsum[0] + wsum[1] + wsum[2] + wsum[3]);
}

// ---------------- launch ----------------
extern "C" void kernel_launch(void* const* d_in, const int* in_sizes, int n_in,
                              void* d_out, int out_size, void* d_ws, size_t ws_size,
                              hipStream_t stream)
{
    const float* node_features = (const float*)d_in[0];
    const float* edge_features = (const float*)d_in[1];
    const float* W_init = (const float*)d_in[2];
    const float* b_init = (const float*)d_in[3];
    const float* W_edge = (const float*)d_in[4];
    const float* b_edge = (const float*)d_in[5];
    const float* Wi_gru = (const float*)d_in[6];
    const float* Wh_gru = (const float*)d_in[7];
    const float* bi_gru = (const float*)d_in[8];
    const float* bh_gru = (const float*)d_in[9];
    const float* W_ri = (const float*)d_in[10];
    const float* b_ri = (const float*)d_in[11];
    const float* W_rj = (const float*)d_in[12];
    const float* b_rj = (const float*)d_in[13];
    const int* receivers = (const int*)d_in[14];
    const int* senders   = (const int*)d_in[15];
    float* out = (float*)d_out;

    // workspace carve: floats then ints; ~60 MB total
    float* fb      = (float*)d_ws;
    float* hidden0 = fb;                 // 400000
    float* hidA    = fb + 400000;        // 400000
    float* hidB    = fb + 800000;        // 400000
    float* tmp     = fb + 1200000;       // 6400000 (E*16, sender-order msgs)
    float* efp     = fb + 7600000;       // 6400000 (E*16, sender-order feats)
    int* ib       = (int*)(fb + 14000000);
    int* cnt      = ib;                  // 25024
    int* row_ptr  = ib + 25024;          // 25024
    int* cursor   = ib + 50048;          // 25024
    int* rcnt     = ib + 75072;          // 25024
    int* rrow_ptr = ib + 100096;         // 25024
    int* rcur     = ib + 125120;         // 25024
    int* eids     = ib + 150144;         // 400000
    int* rpos     = ib + 550144;         // 400000

    dim3 b256(256);
    int grid_n16 = (N_NODES * 16 + 255) / 256;   // 1563
    int grid_e   = (N_EDGES + 255) / 256;        // 1563
    int grid_e16 = (N_EDGES * 16 + 255) / 256;   // 25000
    int grid_n   = (N_NODES + 255) / 256;        // 98
    int grid_msg = (N_NODES + 3) / 4;            // 6250 (1 wave per sender)

    k_init<<<grid_n16, b256, 0, stream>>>(node_features, W_init, b_init,
                                          hidden0, hidA, cnt, rcnt);
    k_hist2<<<grid_e, b256, 0, stream>>>(senders, receivers, cnt, rcnt);
    k_scan2<<<1, 1024, 0, stream>>>(cnt, row_ptr, cursor,
                                    rcnt, rrow_ptr, rcur, out);
    k_scatter2<<<grid_e, b256, 0, stream>>>(senders, receivers, cursor, rcur,
                                            eids, rpos);
    k_permute<<<grid_e16, b256, 0, stream>>>(edge_features, eids, efp);

    float* hin = hidA;
    float* hout = hidB;
    for (int it = 0; it < 3; ++it) {
        k_msg<<<grid_msg, b256, 0, stream>>>(hin, efp,
                                             W_edge, b_edge, row_ptr, tmp);
        k_gru<<<grid_n16, b256, 0, stream>>>(hin, tmp, rrow_ptr, rpos,
                                             Wi_gru, Wh_gru, bi_gru, bh_gru, hout);
        float* t = hin; hin = hout; hout = t;
    }

    k_readout<<<grid_n, b256, 0, stream>>>(hin, hidden0, W_ri, b_ri, W_rj, b_rj, out);
}

// Round 6
// 590.786 us; speedup vs baseline: 1.3299x; 1.3299x over previous
//
#include <hip/hip_runtime.h>

#define N_NODES 25000
#define N_EDGES 400000

// ---------------- fast transcendentals (fp32, ~2ulp) ----------------
__device__ __forceinline__ float fast_sigmoid(float x) {
    return __builtin_amdgcn_rcpf(1.0f + __expf(-x));
}
__device__ __forceinline__ float fast_tanh(float x) {
    return 1.0f - 2.0f * __builtin_amdgcn_rcpf(__expf(2.0f * x) + 1.0f);
}

// lane j receives value from lane j^k within its 32-lane half (k<16 keeps it
// inside the 16-lane node group). BitMode offset = (xor<<10)|(or<<5)|and.
#define SWZF(x, k) __int_as_float(__builtin_amdgcn_ds_swizzle(__float_as_int(x), ((k) << 10) | 0x1F))
// broadcast lane t of each 16-lane group: src = (lane & 0x10) | t
#define BCAST16(x, t) __int_as_float(__builtin_amdgcn_ds_swizzle(__float_as_int(x), ((t) << 5) | 0x10))

// ---------------- K1: hidden0 = nf @ W_init + b_init ; copy; zero cnt/rcnt ---
__global__ void __launch_bounds__(256) k_init(
        const float* __restrict__ nf, const float* __restrict__ Wini,
        const float* __restrict__ bini,
        float* __restrict__ hidden0, float* __restrict__ hid,
        int* __restrict__ cnt, int* __restrict__ rcnt)
{
    int gtid = blockIdx.x * 256 + threadIdx.x;
    if (gtid <= N_NODES) { cnt[gtid] = 0; rcnt[gtid] = 0; }
    int node = gtid >> 4;
    int j = gtid & 15;
    if (node >= N_NODES) return;

    const float4* nf4 = (const float4*)(nf + node * 32);
    float acc = bini[j];
#pragma unroll
    for (int g = 0; g < 8; ++g) {
        float4 v = nf4[g];
        acc = fmaf(v.x, Wini[(g*4+0)*16 + j], acc);
        acc = fmaf(v.y, Wini[(g*4+1)*16 + j], acc);
        acc = fmaf(v.z, Wini[(g*4+2)*16 + j], acc);
        acc = fmaf(v.w, Wini[(g*4+3)*16 + j], acc);
    }
    hidden0[node*16 + j] = acc;
    hid[node*16 + j] = acc;
}

// ---------------- fused CSR builds ----------------
__global__ void __launch_bounds__(256) k_hist2(const int* __restrict__ send,
        const int* __restrict__ recv,
        int* __restrict__ cnt, int* __restrict__ rcnt)
{
    int e = blockIdx.x * 256 + threadIdx.x;
    if (e < N_EDGES) {
        atomicAdd(&cnt[send[e]], 1);
        atomicAdd(&rcnt[recv[e]], 1);
    }
}

// two exclusive scans in one single-block kernel
__global__ void __launch_bounds__(1024) k_scan2(
        const int* __restrict__ cnt,  int* __restrict__ row_ptr,  int* __restrict__ cursor,
        const int* __restrict__ rcnt, int* __restrict__ rrow_ptr, int* __restrict__ rcur,
        float* __restrict__ out)
{
    __shared__ int sums[1024];
    int t = threadIdx.x;
    const int CH = (N_NODES + 1023) / 1024 + 1;   // 25 -> covers 25600

#define SCAN_PASS(SRC, DST0, DST1) { \
        int base = t * CH; \
        int s = 0; \
        for (int i = 0; i < CH; ++i) { \
            int idx = base + i; \
            if (idx < N_NODES) s += SRC[idx]; \
        } \
        sums[t] = s; \
        __syncthreads(); \
        for (int off = 1; off < 1024; off <<= 1) { \
            int add = (t >= off) ? sums[t - off] : 0; \
            __syncthreads(); \
            sums[t] += add; \
            __syncthreads(); \
        } \
        int run = sums[t] - s; \
        for (int i = 0; i < CH; ++i) { \
            int idx = base + i; \
            if (idx < N_NODES) { \
                DST0[idx] = run; \
                DST1[idx] = run; \
                run += SRC[idx]; \
            } \
        } \
        __syncthreads(); }

    SCAN_PASS(cnt, row_ptr, cursor)
    SCAN_PASS(rcnt, rrow_ptr, rcur)
#undef SCAN_PASS

    if (t == 0) {
        row_ptr[N_NODES]  = N_EDGES;
        rrow_ptr[N_NODES] = N_EDGES;
        out[0] = 0.0f;
    }
}

// fused: sender-CSR (eids) + receiver-CSR over sender positions (rpos)
__global__ void __launch_bounds__(256) k_scatter2(const int* __restrict__ send,
        const int* __restrict__ recv,
        int* __restrict__ cursor, int* __restrict__ rcur,
        int* __restrict__ eids, int* __restrict__ rpos)
{
    int e = blockIdx.x * 256 + threadIdx.x;
    if (e < N_EDGES) {
        int pos = atomicAdd(&cursor[send[e]], 1);
        eids[pos] = e;
        int p = atomicAdd(&rcur[recv[e]], 1);
        rpos[p] = pos;
    }
}

// efp[pos,:] = ef[eids[pos],:]  (edge features into sender-CSR order; once)
__global__ void __launch_bounds__(256) k_permute(const float* __restrict__ ef,
        const int* __restrict__ eids, float* __restrict__ efp)
{
    int gtid = blockIdx.x * 256 + threadIdx.x;
    int pos = gtid >> 4;
    int c = gtid & 15;
    if (pos < N_EDGES) efp[(size_t)pos*16 + c] = ef[(size_t)eids[pos]*16 + c];
}

// ---------------- K3: 16 lanes per sender, edge loop unrolled x4 ------------
// group (16 lanes) = one sender s; lane = message dim m. q computed ONCE per
// (s,m) (no redundancy). Edge loop: 4 edges per iteration -> 16 independent
// dwordx4 loads (256B/group in flight, 4x the unrolled-1 version), 4
// independent FMA chains (ILP 4), 4 coalesced 64B stores. All streams
// sequential (efp and tmp both in sender-CSR order).
#define MSG16(E0,E1,E2,E3) ( \
    ( fmaf((E0).w,q[3],  fmaf((E0).z,q[2],  fmaf((E0).y,q[1],  fmaf((E0).x,q[0],  qb)))) \
    + fmaf((E1).w,q[7],  fmaf((E1).z,q[6],  fmaf((E1).y,q[5],  fmaf((E1).x,q[4],  0.0f)))) ) \
  + ( fmaf((E2).w,q[11], fmaf((E2).z,q[10], fmaf((E2).y,q[9],  fmaf((E2).x,q[8],  0.0f)))) \
    + fmaf((E3).w,q[15], fmaf((E3).z,q[14], fmaf((E3).y,q[13], fmaf((E3).x,q[12], 0.0f)))) ) )

__global__ void __launch_bounds__(256) k_msg(
        const float* __restrict__ hid, const float* __restrict__ efp,
        const float* __restrict__ We, const float* __restrict__ be,
        const int* __restrict__ row_ptr,
        float* __restrict__ tmp)
{
    int gtid = blockIdx.x * 256 + threadIdx.x;
    int s = gtid >> 4;
    int m = gtid & 15;
    if (s >= N_NODES) return;

    float h[16];
    {
        const float4* h4 = (const float4*)(hid + s*16);
        float4 a = h4[0], b = h4[1], c = h4[2], d = h4[3];
        h[0]=a.x; h[1]=a.y; h[2]=a.z;  h[3]=a.w;
        h[4]=b.x; h[5]=b.y; h[6]=b.z;  h[7]=b.w;
        h[8]=c.x; h[9]=c.y; h[10]=c.z; h[11]=c.w;
        h[12]=d.x; h[13]=d.y; h[14]=d.z; h[15]=d.w;
    }
    float q[16];
#pragma unroll
    for (int f = 0; f < 16; ++f) {
        const float4* wf = (const float4*)(We + f*256 + m*16);
        float4 a = wf[0], b = wf[1], c = wf[2], d = wf[3];
        float acc;
        acc  = a.x*h[0]  + a.y*h[1]  + a.z*h[2]  + a.w*h[3];
        acc += b.x*h[4]  + b.y*h[5]  + b.z*h[6]  + b.w*h[7];
        acc += c.x*h[8]  + c.y*h[9]  + c.z*h[10] + c.w*h[11];
        acc += d.x*h[12] + d.y*h[13] + d.z*h[14] + d.w*h[15];
        q[f] = acc;
    }
    float qb;
    {
        const float4* bf = (const float4*)(be + m*16);
        float4 a = bf[0], b = bf[1], c = bf[2], d = bf[3];
        qb  = a.x*h[0]  + a.y*h[1]  + a.z*h[2]  + a.w*h[3];
        qb += b.x*h[4]  + b.y*h[5]  + b.z*h[6]  + b.w*h[7];
        qb += c.x*h[8]  + c.y*h[9]  + c.z*h[10] + c.w*h[11];
        qb += d.x*h[12] + d.y*h[13] + d.z*h[14] + d.w*h[15];
    }

    int beg = row_ptr[s];
    int end = row_ptr[s + 1];
    int i = beg;
    for (; i + 4 <= end; i += 4) {
        const float4* p0 = (const float4*)(efp + (size_t)(i+0)*16);
        const float4* p1 = (const float4*)(efp + (size_t)(i+1)*16);
        const float4* p2 = (const float4*)(efp + (size_t)(i+2)*16);
        const float4* p3 = (const float4*)(efp + (size_t)(i+3)*16);
        float4 A0=p0[0], A1=p0[1], A2=p0[2], A3=p0[3];
        float4 B0=p1[0], B1=p1[1], B2=p1[2], B3=p1[3];
        float4 C0=p2[0], C1=p2[1], C2=p2[2], C3=p2[3];
        float4 D0=p3[0], D1=p3[1], D2=p3[2], D3=p3[3];
        float v0 = MSG16(A0, A1, A2, A3);
        float v1 = MSG16(B0, B1, B2, B3);
        float v2 = MSG16(C0, C1, C2, C3);
        float v3 = MSG16(D0, D1, D2, D3);
        tmp[(size_t)(i+0)*16 + m] = v0;
        tmp[(size_t)(i+1)*16 + m] = v1;
        tmp[(size_t)(i+2)*16 + m] = v2;
        tmp[(size_t)(i+3)*16 + m] = v3;
    }
    for (; i < end; ++i) {
        const float4* e4 = (const float4*)(efp + (size_t)i*16);
        float4 E0 = e4[0], E1 = e4[1], E2 = e4[2], E3 = e4[3];
        tmp[(size_t)i*16 + m] = MSG16(E0, E1, E2, E3);
    }
}

// ---------------- K4: line-gather + GRU (T=32), 2 scalars/lane ---------------
// 16 lanes per node, lane j = GRU unit j. In-edges listed by rpos (receiver-
// CSR over sender positions): lane j reads ONLY dword j of each 64B message
// line -> group fetches each line exactly once (tmp is L3-resident).
// Gather unrolled x8 with 4 accumulators for MLP.
__global__ void __launch_bounds__(256) k_gru(
        const float* __restrict__ hid_in, const float* __restrict__ tmp,
        const int* __restrict__ rrow_ptr, const int* __restrict__ rpos,
        const float* __restrict__ Wi, const float* __restrict__ Wh,
        const float* __restrict__ bi, const float* __restrict__ bh,
        float* __restrict__ hid_out)
{
    int gtid = blockIdx.x * 256 + threadIdx.x;
    int node = gtid >> 4;
    int j = gtid & 15;
    if (node >= N_NODES) return;

    float s0 = 0.0f, s1 = 0.0f, s2 = 0.0f, s3 = 0.0f;
    {
        int beg = rrow_ptr[node];
        int end = rrow_ptr[node + 1];
        int d = end - beg;
        int i = 0;
        for (; i + 8 <= d; i += 8) {
            int p0 = rpos[beg + i + 0];
            int p1 = rpos[beg + i + 1];
            int p2 = rpos[beg + i + 2];
            int p3 = rpos[beg + i + 3];
            int p4 = rpos[beg + i + 4];
            int p5 = rpos[beg + i + 5];
            int p6 = rpos[beg + i + 6];
            int p7 = rpos[beg + i + 7];
            float a0 = tmp[(size_t)p0*16 + j];
            float a1 = tmp[(size_t)p1*16 + j];
            float a2 = tmp[(size_t)p2*16 + j];
            float a3 = tmp[(size_t)p3*16 + j];
            float a4 = tmp[(size_t)p4*16 + j];
            float a5 = tmp[(size_t)p5*16 + j];
            float a6 = tmp[(size_t)p6*16 + j];
            float a7 = tmp[(size_t)p7*16 + j];
            s0 += a0; s1 += a1; s2 += a2; s3 += a3;
            s0 += a4; s1 += a5; s2 += a6; s3 += a7;
        }
        for (; i < d; ++i) s0 += tmp[(size_t)rpos[beg + i]*16 + j];
    }
    float msg_own = (s0 + s1) + (s2 + s3);
    float h_own = hid_in[node*16 + j];

    float Wz[16], Wr[16], Wc[16];
#pragma unroll
    for (int k = 0; k < 16; ++k) {
        int l = j ^ k;
        Wz[k] = Wh[l*48 + j];
        Wr[k] = Wh[l*48 + 16 + j];
        Wc[k] = Wh[l*48 + 32 + j];
    }
    float Wiz = Wi[j], Wir = Wi[16+j], Wih = Wi[32+j];
    float cz   = bi[j] + bh[j];
    float cr   = bi[16+j] + bh[16+j];
    float bih_ = bi[32+j];
    float bhh_ = bh[32+j];

    float hn = 0.0f;

#define STEPK(k) { float v = SWZF(hn, k); \
        az = fmaf(v, Wz[k], az); ar = fmaf(v, Wr[k], ar); ac = fmaf(v, Wc[k], ac); }

#define GRUSTEP(XV) { \
        float xv = (XV); \
        float az = fmaf(xv, Wiz, cz); \
        float ar = fmaf(xv, Wir, cr); \
        float ac = bhh_; \
        az = fmaf(hn, Wz[0], az); \
        ar = fmaf(hn, Wr[0], ar); \
        ac = fmaf(hn, Wc[0], ac); \
        STEPK(1)  STEPK(2)  STEPK(3)  STEPK(4)  STEPK(5) \
        STEPK(6)  STEPK(7)  STEPK(8)  STEPK(9)  STEPK(10) \
        STEPK(11) STEPK(12) STEPK(13) STEPK(14) STEPK(15) \
        float z  = fast_sigmoid(az); \
        float r  = fast_sigmoid(ar); \
        float hc = fast_tanh(fmaf(xv, Wih, bih_) + r * ac); \
        hn = fmaf(z, hn - hc, hc); }

    // t = 0..15: x_t = hidden[node][t]
    GRUSTEP(BCAST16(h_own, 0))  GRUSTEP(BCAST16(h_own, 1))
    GRUSTEP(BCAST16(h_own, 2))  GRUSTEP(BCAST16(h_own, 3))
    GRUSTEP(BCAST16(h_own, 4))  GRUSTEP(BCAST16(h_own, 5))
    GRUSTEP(BCAST16(h_own, 6))  GRUSTEP(BCAST16(h_own, 7))
    GRUSTEP(BCAST16(h_own, 8))  GRUSTEP(BCAST16(h_own, 9))
    GRUSTEP(BCAST16(h_own, 10)) GRUSTEP(BCAST16(h_own, 11))
    GRUSTEP(BCAST16(h_own, 12)) GRUSTEP(BCAST16(h_own, 13))
    GRUSTEP(BCAST16(h_own, 14)) GRUSTEP(BCAST16(h_own, 15))
    // t = 16..31: x_t = messages[node][t-16]
    GRUSTEP(BCAST16(msg_own, 0))  GRUSTEP(BCAST16(msg_own, 1))
    GRUSTEP(BCAST16(msg_own, 2))  GRUSTEP(BCAST16(msg_own, 3))
    GRUSTEP(BCAST16(msg_own, 4))  GRUSTEP(BCAST16(msg_own, 5))
    GRUSTEP(BCAST16(msg_own, 6))  GRUSTEP(BCAST16(msg_own, 7))
    GRUSTEP(BCAST16(msg_own, 8))  GRUSTEP(BCAST16(msg_own, 9))
    GRUSTEP(BCAST16(msg_own, 10)) GRUSTEP(BCAST16(msg_own, 11))
    GRUSTEP(BCAST16(msg_own, 12)) GRUSTEP(BCAST16(msg_own, 13))
    GRUSTEP(BCAST16(msg_own, 14)) GRUSTEP(BCAST16(msg_own, 15))
#undef GRUSTEP
#undef STEPK

    hid_out[node*16 + j] = hn;
}

// ---------------- K5: readout ----------------
__global__ void __launch_bounds__(256) k_readout(
        const float* __restrict__ hid, const float* __restrict__ hid0,
        const float* __restrict__ Wri, const float* __restrict__ bri,
        const float* __restrict__ Wrj, const float* __restrict__ brj,
        float* __restrict__ out)
{
    int n = blockIdx.x * 256 + threadIdx.x;
    float val = 0.0f;
    if (n < N_NODES) {
        const float4* h4 = (const float4*)(hid + n * 16);
        const float4* g4 = (const float4*)(hid0 + n * 16);
        float iv = bri[0];
        float jv = brj[0];
#pragma unroll
        for (int g = 0; g < 4; ++g) {
            float4 h  = h4[g];
            float4 h0 = g4[g];
            iv = fmaf(h.x,  Wri[g*4+0], iv);  iv = fmaf(h.y,  Wri[g*4+1], iv);
            iv = fmaf(h.z,  Wri[g*4+2], iv);  iv = fmaf(h.w,  Wri[g*4+3], iv);
            iv = fmaf(h0.x, Wri[16+g*4+0], iv); iv = fmaf(h0.y, Wri[16+g*4+1], iv);
            iv = fmaf(h0.z, Wri[16+g*4+2], iv); iv = fmaf(h0.w, Wri[16+g*4+3], iv);
            jv = fmaf(h.x,  Wrj[g*4+0], jv);  jv = fmaf(h.y,  Wrj[g*4+1], jv);
            jv = fmaf(h.z,  Wrj[g*4+2], jv);  jv = fmaf(h.w,  Wrj[g*4+3], jv);
        }
        val = iv * jv;
    }
#pragma unroll
    for (int off = 32; off > 0; off >>= 1)
        val += __shfl_xor(val, off, 64);
    __shared__ float wsum[4];
    int w = threadIdx.x >> 6;
    if ((threadIdx.x & 63) == 0) wsum[w] = val;
    __syncthreads();
    if (threadIdx.x == 0)
        atomicAdd(out, wsum[0] + wsum[1] + wsum[2] + wsum[3]);
}

// ---------------- launch ----------------
extern "C" void kernel_launch(void* const* d_in, const int* in_sizes, int n_in,
                              void* d_out, int out_size, void* d_ws, size_t ws_size,
                              hipStream_t stream)
{
    const float* node_features = (const float*)d_in[0];
    const float* edge_features = (const float*)d_in[1];
    const float* W_init = (const float*)d_in[2];
    const float* b_init = (const float*)d_in[3];
    const float* W_edge = (const float*)d_in[4];
    const float* b_edge = (const float*)d_in[5];
    const float* Wi_gru = (const float*)d_in[6];
    const float* Wh_gru = (const float*)d_in[7];
    const float* bi_gru = (const float*)d_in[8];
    const float* bh_gru = (const float*)d_in[9];
    const float* W_ri = (const float*)d_in[10];
    const float* b_ri = (const float*)d_in[11];
    const float* W_rj = (const float*)d_in[12];
    const float* b_rj = (const float*)d_in[13];
    const int* receivers = (const int*)d_in[14];
    const int* senders   = (const int*)d_in[15];
    float* out = (float*)d_out;

    // workspace carve: floats then ints; ~60 MB total
    float* fb      = (float*)d_ws;
    float* hidden0 = fb;                 // 400000
    float* hidA    = fb + 400000;        // 400000
    float* hidB    = fb + 800000;        // 400000
    float* tmp     = fb + 1200000;       // 6400000 (E*16, sender-order msgs)
    float* efp     = fb + 7600000;       // 6400000 (E*16, sender-order feats)
    int* ib       = (int*)(fb + 14000000);
    int* cnt      = ib;                  // 25024
    int* row_ptr  = ib + 25024;          // 25024
    int* cursor   = ib + 50048;          // 25024
    int* rcnt     = ib + 75072;          // 25024
    int* rrow_ptr = ib + 100096;         // 25024
    int* rcur     = ib + 125120;         // 25024
    int* eids     = ib + 150144;         // 400000
    int* rpos     = ib + 550144;         // 400000

    dim3 b256(256);
    int grid_n16 = (N_NODES * 16 + 255) / 256;   // 1563
    int grid_e   = (N_EDGES + 255) / 256;        // 1563
    int grid_e16 = (N_EDGES * 16 + 255) / 256;   // 25000
    int grid_n   = (N_NODES + 255) / 256;        // 98

    k_init<<<grid_n16, b256, 0, stream>>>(node_features, W_init, b_init,
                                          hidden0, hidA, cnt, rcnt);
    k_hist2<<<grid_e, b256, 0, stream>>>(senders, receivers, cnt, rcnt);
    k_scan2<<<1, 1024, 0, stream>>>(cnt, row_ptr, cursor,
                                    rcnt, rrow_ptr, rcur, out);
    k_scatter2<<<grid_e, b256, 0, stream>>>(senders, receivers, cursor, rcur,
                                            eids, rpos);
    k_permute<<<grid_e16, b256, 0, stream>>>(edge_features, eids, efp);

    float* hin = hidA;
    float* hout = hidB;
    for (int it = 0; it < 3; ++it) {
        k_msg<<<grid_n16, b256, 0, stream>>>(hin, efp,
                                             W_edge, b_edge, row_ptr, tmp);
        k_gru<<<grid_n16, b256, 0, stream>>>(hin, tmp, rrow_ptr, rpos,
                                             Wi_gru, Wh_gru, bi_gru, bh_gru, hout);
        float* t = hin; hin = hout; hout = t;
    }

    k_readout<<<grid_n, b256, 0, stream>>>(hin, hidden0, W_ri, b_ri, W_rj, b_rj, out);
}

// Round 7
// 496.801 us; speedup vs baseline: 1.5815x; 1.1892x over previous
//
#include <hip/hip_runtime.h>

#define N_NODES 25000
#define N_EDGES 400000

// ---------------- fast transcendentals (fp32, ~2ulp) ----------------
__device__ __forceinline__ float fast_sigmoid(float x) {
    return __builtin_amdgcn_rcpf(1.0f + __expf(-x));
}
__device__ __forceinline__ float fast_tanh(float x) {
    return 1.0f - 2.0f * __builtin_amdgcn_rcpf(__expf(2.0f * x) + 1.0f);
}

// lane j receives value from lane j^k within its 32-lane half (k<16 keeps it
// inside the 16-lane node group). BitMode offset = (xor<<10)|(or<<5)|and.
#define SWZF(x, k) __int_as_float(__builtin_amdgcn_ds_swizzle(__float_as_int(x), ((k) << 10) | 0x1F))
// broadcast lane t of each 16-lane group: src = (lane & 0x10) | t
#define BCAST16(x, t) __int_as_float(__builtin_amdgcn_ds_swizzle(__float_as_int(x), ((t) << 5) | 0x10))

// ---------------- K1: hidden0 = nf @ W_init + b_init ; copy; zero cnt/rcnt ---
__global__ void __launch_bounds__(256) k_init(
        const float* __restrict__ nf, const float* __restrict__ Wini,
        const float* __restrict__ bini,
        float* __restrict__ hidden0, float* __restrict__ hid,
        int* __restrict__ cnt, int* __restrict__ rcnt)
{
    int gtid = blockIdx.x * 256 + threadIdx.x;
    if (gtid <= N_NODES) { cnt[gtid] = 0; rcnt[gtid] = 0; }
    int node = gtid >> 4;
    int j = gtid & 15;
    if (node >= N_NODES) return;

    const float4* nf4 = (const float4*)(nf + node * 32);
    float acc = bini[j];
#pragma unroll
    for (int g = 0; g < 8; ++g) {
        float4 v = nf4[g];
        acc = fmaf(v.x, Wini[(g*4+0)*16 + j], acc);
        acc = fmaf(v.y, Wini[(g*4+1)*16 + j], acc);
        acc = fmaf(v.z, Wini[(g*4+2)*16 + j], acc);
        acc = fmaf(v.w, Wini[(g*4+3)*16 + j], acc);
    }
    hidden0[node*16 + j] = acc;
    hid[node*16 + j] = acc;
}

// ---------------- fused CSR builds ----------------
__global__ void __launch_bounds__(256) k_hist2(const int* __restrict__ send,
        const int* __restrict__ recv,
        int* __restrict__ cnt, int* __restrict__ rcnt)
{
    int e = blockIdx.x * 256 + threadIdx.x;
    if (e < N_EDGES) {
        atomicAdd(&cnt[send[e]], 1);
        atomicAdd(&rcnt[recv[e]], 1);
    }
}

// Two independent exclusive scans, one per block.
// LDS-staged for coalescing: the old version read SRC[t*25+i] (consecutive
// threads 100B apart -> every 4B load its own cache line; single-CU
// miss-throughput bound => 98us). Now: stride-1024 coalesced global loads
// into LDS (100KB), all strided work in LDS, coalesced stores out.
#define SCAN_TOT 25600                      // 1024 * 25
__global__ void __launch_bounds__(1024) k_scan2(
        const int* __restrict__ cnt,  int* __restrict__ row_ptr,  int* __restrict__ cursor,
        const int* __restrict__ rcnt, int* __restrict__ rrow_ptr, int* __restrict__ rcur,
        float* __restrict__ out)
{
    __shared__ int data[SCAN_TOT];          // 100 KB
    __shared__ int sums[1024];              // 4 KB
    int t = threadIdx.x;
    const int CH = 25;

    const int* SRC = blockIdx.x ? rcnt : cnt;
    int* DST0 = blockIdx.x ? rrow_ptr : row_ptr;
    int* DST1 = blockIdx.x ? rcur : cursor;

    // coalesced load (pad tail with 0)
    for (int i = t; i < SCAN_TOT; i += 1024)
        data[i] = (i < N_NODES) ? SRC[i] : 0;
    __syncthreads();

    // per-thread chunk sum (stride-25 in LDS: odd stride -> only free 2-way aliasing)
    int base = t * CH;
    int s = 0;
#pragma unroll
    for (int i = 0; i < CH; ++i) s += data[base + i];
    sums[t] = s;
    __syncthreads();

    // Hillis-Steele inclusive scan over the 1024 chunk sums
    for (int off = 1; off < 1024; off <<= 1) {
        int add = (t >= off) ? sums[t - off] : 0;
        __syncthreads();
        sums[t] += add;
        __syncthreads();
    }
    int run = sums[t] - s;                  // exclusive prefix at chunk start

    // overwrite data[] with exclusive running values
#pragma unroll
    for (int i = 0; i < CH; ++i) {
        int v = data[base + i];
        data[base + i] = run;
        run += v;
    }
    __syncthreads();

    // coalesced stores
    for (int i = t; i < N_NODES; i += 1024) {
        int v = data[i];
        DST0[i] = v;
        DST1[i] = v;
    }
    if (t == 0) {
        if (blockIdx.x == 0) { row_ptr[N_NODES] = N_EDGES; out[0] = 0.0f; }
        else                 { rrow_ptr[N_NODES] = N_EDGES; }
    }
}

// fused: sender-CSR (eids) + receiver-CSR over sender positions (rpos)
__global__ void __launch_bounds__(256) k_scatter2(const int* __restrict__ send,
        const int* __restrict__ recv,
        int* __restrict__ cursor, int* __restrict__ rcur,
        int* __restrict__ eids, int* __restrict__ rpos)
{
    int e = blockIdx.x * 256 + threadIdx.x;
    if (e < N_EDGES) {
        int pos = atomicAdd(&cursor[send[e]], 1);
        eids[pos] = e;
        int p = atomicAdd(&rcur[recv[e]], 1);
        rpos[p] = pos;
    }
}

// efp[pos,:] = ef[eids[pos],:]  (edge features into sender-CSR order; once)
__global__ void __launch_bounds__(256) k_permute(const float* __restrict__ ef,
        const int* __restrict__ eids, float* __restrict__ efp)
{
    int gtid = blockIdx.x * 256 + threadIdx.x;
    int pos = gtid >> 4;
    int c = gtid & 15;
    if (pos < N_EDGES) efp[(size_t)pos*16 + c] = ef[(size_t)eids[pos]*16 + c];
}

// ---------------- K3: 16 lanes per sender, edge loop unrolled x4 ------------
// group (16 lanes) = one sender s; lane = message dim m. q computed ONCE per
// (s,m). Edge loop: 4 edges per iteration -> 16 independent dwordx4 loads
// (256B/group in flight), 4 independent FMA chains (ILP 4), 4 coalesced 64B
// stores. All streams sequential (efp and tmp both in sender-CSR order).
#define MSG16(E0,E1,E2,E3) ( \
    ( fmaf((E0).w,q[3],  fmaf((E0).z,q[2],  fmaf((E0).y,q[1],  fmaf((E0).x,q[0],  qb)))) \
    + fmaf((E1).w,q[7],  fmaf((E1).z,q[6],  fmaf((E1).y,q[5],  fmaf((E1).x,q[4],  0.0f)))) ) \
  + ( fmaf((E2).w,q[11], fmaf((E2).z,q[10], fmaf((E2).y,q[9],  fmaf((E2).x,q[8],  0.0f)))) \
    + fmaf((E3).w,q[15], fmaf((E3).z,q[14], fmaf((E3).y,q[13], fmaf((E3).x,q[12], 0.0f)))) ) )

__global__ void __launch_bounds__(256) k_msg(
        const float* __restrict__ hid, const float* __restrict__ efp,
        const float* __restrict__ We, const float* __restrict__ be,
        const int* __restrict__ row_ptr,
        float* __restrict__ tmp)
{
    int gtid = blockIdx.x * 256 + threadIdx.x;
    int s = gtid >> 4;
    int m = gtid & 15;
    if (s >= N_NODES) return;

    float h[16];
    {
        const float4* h4 = (const float4*)(hid + s*16);
        float4 a = h4[0], b = h4[1], c = h4[2], d = h4[3];
        h[0]=a.x; h[1]=a.y; h[2]=a.z;  h[3]=a.w;
        h[4]=b.x; h[5]=b.y; h[6]=b.z;  h[7]=b.w;
        h[8]=c.x; h[9]=c.y; h[10]=c.z; h[11]=c.w;
        h[12]=d.x; h[13]=d.y; h[14]=d.z; h[15]=d.w;
    }
    float q[16];
#pragma unroll
    for (int f = 0; f < 16; ++f) {
        const float4* wf = (const float4*)(We + f*256 + m*16);
        float4 a = wf[0], b = wf[1], c = wf[2], d = wf[3];
        float acc;
        acc  = a.x*h[0]  + a.y*h[1]  + a.z*h[2]  + a.w*h[3];
        acc += b.x*h[4]  + b.y*h[5]  + b.z*h[6]  + b.w*h[7];
        acc += c.x*h[8]  + c.y*h[9]  + c.z*h[10] + c.w*h[11];
        acc += d.x*h[12] + d.y*h[13] + d.z*h[14] + d.w*h[15];
        q[f] = acc;
    }
    float qb;
    {
        const float4* bf = (const float4*)(be + m*16);
        float4 a = bf[0], b = bf[1], c = bf[2], d = bf[3];
        qb  = a.x*h[0]  + a.y*h[1]  + a.z*h[2]  + a.w*h[3];
        qb += b.x*h[4]  + b.y*h[5]  + b.z*h[6]  + b.w*h[7];
        qb += c.x*h[8]  + c.y*h[9]  + c.z*h[10] + c.w*h[11];
        qb += d.x*h[12] + d.y*h[13] + d.z*h[14] + d.w*h[15];
    }

    int beg = row_ptr[s];
    int end = row_ptr[s + 1];
    int i = beg;
    for (; i + 4 <= end; i += 4) {
        const float4* p0 = (const float4*)(efp + (size_t)(i+0)*16);
        const float4* p1 = (const float4*)(efp + (size_t)(i+1)*16);
        const float4* p2 = (const float4*)(efp + (size_t)(i+2)*16);
        const float4* p3 = (const float4*)(efp + (size_t)(i+3)*16);
        float4 A0=p0[0], A1=p0[1], A2=p0[2], A3=p0[3];
        float4 B0=p1[0], B1=p1[1], B2=p1[2], B3=p1[3];
        float4 C0=p2[0], C1=p2[1], C2=p2[2], C3=p2[3];
        float4 D0=p3[0], D1=p3[1], D2=p3[2], D3=p3[3];
        float v0 = MSG16(A0, A1, A2, A3);
        float v1 = MSG16(B0, B1, B2, B3);
        float v2 = MSG16(C0, C1, C2, C3);
        float v3 = MSG16(D0, D1, D2, D3);
        tmp[(size_t)(i+0)*16 + m] = v0;
        tmp[(size_t)(i+1)*16 + m] = v1;
        tmp[(size_t)(i+2)*16 + m] = v2;
        tmp[(size_t)(i+3)*16 + m] = v3;
    }
    for (; i < end; ++i) {
        const float4* e4 = (const float4*)(efp + (size_t)i*16);
        float4 E0 = e4[0], E1 = e4[1], E2 = e4[2], E3 = e4[3];
        tmp[(size_t)i*16 + m] = MSG16(E0, E1, E2, E3);
    }
}

// ---------------- K4: line-gather + GRU (T=32), 2 scalars/lane ---------------
// 16 lanes per node, lane j = GRU unit j. In-edges listed by rpos (receiver-
// CSR over sender positions): lane j reads ONLY dword j of each 64B message
// line -> group fetches each line exactly once (tmp is L3-resident).
// Gather unrolled x8 with 4 accumulators for MLP.
__global__ void __launch_bounds__(256) k_gru(
        const float* __restrict__ hid_in, const float* __restrict__ tmp,
        const int* __restrict__ rrow_ptr, const int* __restrict__ rpos,
        const float* __restrict__ Wi, const float* __restrict__ Wh,
        const float* __restrict__ bi, const float* __restrict__ bh,
        float* __restrict__ hid_out)
{
    int gtid = blockIdx.x * 256 + threadIdx.x;
    int node = gtid >> 4;
    int j = gtid & 15;
    if (node >= N_NODES) return;

    float s0 = 0.0f, s1 = 0.0f, s2 = 0.0f, s3 = 0.0f;
    {
        int beg = rrow_ptr[node];
        int end = rrow_ptr[node + 1];
        int d = end - beg;
        int i = 0;
        for (; i + 8 <= d; i += 8) {
            int p0 = rpos[beg + i + 0];
            int p1 = rpos[beg + i + 1];
            int p2 = rpos[beg + i + 2];
            int p3 = rpos[beg + i + 3];
            int p4 = rpos[beg + i + 4];
            int p5 = rpos[beg + i + 5];
            int p6 = rpos[beg + i + 6];
            int p7 = rpos[beg + i + 7];
            float a0 = tmp[(size_t)p0*16 + j];
            float a1 = tmp[(size_t)p1*16 + j];
            float a2 = tmp[(size_t)p2*16 + j];
            float a3 = tmp[(size_t)p3*16 + j];
            float a4 = tmp[(size_t)p4*16 + j];
            float a5 = tmp[(size_t)p5*16 + j];
            float a6 = tmp[(size_t)p6*16 + j];
            float a7 = tmp[(size_t)p7*16 + j];
            s0 += a0; s1 += a1; s2 += a2; s3 += a3;
            s0 += a4; s1 += a5; s2 += a6; s3 += a7;
        }
        for (; i < d; ++i) s0 += tmp[(size_t)rpos[beg + i]*16 + j];
    }
    float msg_own = (s0 + s1) + (s2 + s3);
    float h_own = hid_in[node*16 + j];

    float Wz[16], Wr[16], Wc[16];
#pragma unroll
    for (int k = 0; k < 16; ++k) {
        int l = j ^ k;
        Wz[k] = Wh[l*48 + j];
        Wr[k] = Wh[l*48 + 16 + j];
        Wc[k] = Wh[l*48 + 32 + j];
    }
    float Wiz = Wi[j], Wir = Wi[16+j], Wih = Wi[32+j];
    float cz   = bi[j] + bh[j];
    float cr   = bi[16+j] + bh[16+j];
    float bih_ = bi[32+j];
    float bhh_ = bh[32+j];

    float hn = 0.0f;

#define STEPK(k) { float v = SWZF(hn, k); \
        az = fmaf(v, Wz[k], az); ar = fmaf(v, Wr[k], ar); ac = fmaf(v, Wc[k], ac); }

#define GRUSTEP(XV) { \
        float xv = (XV); \
        float az = fmaf(xv, Wiz, cz); \
        float ar = fmaf(xv, Wir, cr); \
        float ac = bhh_; \
        az = fmaf(hn, Wz[0], az); \
        ar = fmaf(hn, Wr[0], ar); \
        ac = fmaf(hn, Wc[0], ac); \
        STEPK(1)  STEPK(2)  STEPK(3)  STEPK(4)  STEPK(5) \
        STEPK(6)  STEPK(7)  STEPK(8)  STEPK(9)  STEPK(10) \
        STEPK(11) STEPK(12) STEPK(13) STEPK(14) STEPK(15) \
        float z  = fast_sigmoid(az); \
        float r  = fast_sigmoid(ar); \
        float hc = fast_tanh(fmaf(xv, Wih, bih_) + r * ac); \
        hn = fmaf(z, hn - hc, hc); }

    // t = 0..15: x_t = hidden[node][t]
    GRUSTEP(BCAST16(h_own, 0))  GRUSTEP(BCAST16(h_own, 1))
    GRUSTEP(BCAST16(h_own, 2))  GRUSTEP(BCAST16(h_own, 3))
    GRUSTEP(BCAST16(h_own, 4))  GRUSTEP(BCAST16(h_own, 5))
    GRUSTEP(BCAST16(h_own, 6))  GRUSTEP(BCAST16(h_own, 7))
    GRUSTEP(BCAST16(h_own, 8))  GRUSTEP(BCAST16(h_own, 9))
    GRUSTEP(BCAST16(h_own, 10)) GRUSTEP(BCAST16(h_own, 11))
    GRUSTEP(BCAST16(h_own, 12)) GRUSTEP(BCAST16(h_own, 13))
    GRUSTEP(BCAST16(h_own, 14)) GRUSTEP(BCAST16(h_own, 15))
    // t = 16..31: x_t = messages[node][t-16]
    GRUSTEP(BCAST16(msg_own, 0))  GRUSTEP(BCAST16(msg_own, 1))
    GRUSTEP(BCAST16(msg_own, 2))  GRUSTEP(BCAST16(msg_own, 3))
    GRUSTEP(BCAST16(msg_own, 4))  GRUSTEP(BCAST16(msg_own, 5))
    GRUSTEP(BCAST16(msg_own, 6))  GRUSTEP(BCAST16(msg_own, 7))
    GRUSTEP(BCAST16(msg_own, 8))  GRUSTEP(BCAST16(msg_own, 9))
    GRUSTEP(BCAST16(msg_own, 10)) GRUSTEP(BCAST16(msg_own, 11))
    GRUSTEP(BCAST16(msg_own, 12)) GRUSTEP(BCAST16(msg_own, 13))
    GRUSTEP(BCAST16(msg_own, 14)) GRUSTEP(BCAST16(msg_own, 15))
#undef GRUSTEP
#undef STEPK

    hid_out[node*16 + j] = hn;
}

// ---------------- K5: readout ----------------
__global__ void __launch_bounds__(256) k_readout(
        const float* __restrict__ hid, const float* __restrict__ hid0,
        const float* __restrict__ Wri, const float* __restrict__ bri,
        const float* __restrict__ Wrj, const float* __restrict__ brj,
        float* __restrict__ out)
{
    int n = blockIdx.x * 256 + threadIdx.x;
    float val = 0.0f;
    if (n < N_NODES) {
        const float4* h4 = (const float4*)(hid + n * 16);
        const float4* g4 = (const float4*)(hid0 + n * 16);
        float iv = bri[0];
        float jv = brj[0];
#pragma unroll
        for (int g = 0; g < 4; ++g) {
            float4 h  = h4[g];
            float4 h0 = g4[g];
            iv = fmaf(h.x,  Wri[g*4+0], iv);  iv = fmaf(h.y,  Wri[g*4+1], iv);
            iv = fmaf(h.z,  Wri[g*4+2], iv);  iv = fmaf(h.w,  Wri[g*4+3], iv);
            iv = fmaf(h0.x, Wri[16+g*4+0], iv); iv = fmaf(h0.y, Wri[16+g*4+1], iv);
            iv = fmaf(h0.z, Wri[16+g*4+2], iv); iv = fmaf(h0.w, Wri[16+g*4+3], iv);
            jv = fmaf(h.x,  Wrj[g*4+0], jv);  jv = fmaf(h.y,  Wrj[g*4+1], jv);
            jv = fmaf(h.z,  Wrj[g*4+2], jv);  jv = fmaf(h.w,  Wrj[g*4+3], jv);
        }
        val = iv * jv;
    }
#pragma unroll
    for (int off = 32; off > 0; off >>= 1)
        val += __shfl_xor(val, off, 64);
    __shared__ float wsum[4];
    int w = threadIdx.x >> 6;
    if ((threadIdx.x & 63) == 0) wsum[w] = val;
    __syncthreads();
    if (threadIdx.x == 0)
        atomicAdd(out, wsum[0] + wsum[1] + wsum[2] + wsum[3]);
}

// ---------------- launch ----------------
extern "C" void kernel_launch(void* const* d_in, const int* in_sizes, int n_in,
                              void* d_out, int out_size, void* d_ws, size_t ws_size,
                              hipStream_t stream)
{
    const float* node_features = (const float*)d_in[0];
    const float* edge_features = (const float*)d_in[1];
    const float* W_init = (const float*)d_in[2];
    const float* b_init = (const float*)d_in[3];
    const float* W_edge = (const float*)d_in[4];
    const float* b_edge = (const float*)d_in[5];
    const float* Wi_gru = (const float*)d_in[6];
    const float* Wh_gru = (const float*)d_in[7];
    const float* bi_gru = (const float*)d_in[8];
    const float* bh_gru = (const float*)d_in[9];
    const float* W_ri = (const float*)d_in[10];
    const float* b_ri = (const float*)d_in[11];
    const float* W_rj = (const float*)d_in[12];
    const float* b_rj = (const float*)d_in[13];
    const int* receivers = (const int*)d_in[14];
    const int* senders   = (const int*)d_in[15];
    float* out = (float*)d_out;

    // workspace carve: floats then ints; ~60 MB total
    float* fb      = (float*)d_ws;
    float* hidden0 = fb;                 // 400000
    float* hidA    = fb + 400000;        // 400000
    float* hidB    = fb + 800000;        // 400000
    float* tmp     = fb + 1200000;       // 6400000 (E*16, sender-order msgs)
    float* efp     = fb + 7600000;       // 6400000 (E*16, sender-order feats)
    int* ib       = (int*)(fb + 14000000);
    int* cnt      = ib;                  // 25024
    int* row_ptr  = ib + 25024;          // 25024
    int* cursor   = ib + 50048;          // 25024
    int* rcnt     = ib + 75072;          // 25024
    int* rrow_ptr = ib + 100096;         // 25024
    int* rcur     = ib + 125120;         // 25024
    int* eids     = ib + 150144;         // 400000
    int* rpos     = ib + 550144;         // 400000

    dim3 b256(256);
    int grid_n16 = (N_NODES * 16 + 255) / 256;   // 1563
    int grid_e   = (N_EDGES + 255) / 256;        // 1563
    int grid_e16 = (N_EDGES * 16 + 255) / 256;   // 25000
    int grid_n   = (N_NODES + 255) / 256;        // 98

    k_init<<<grid_n16, b256, 0, stream>>>(node_features, W_init, b_init,
                                          hidden0, hidA, cnt, rcnt);
    k_hist2<<<grid_e, b256, 0, stream>>>(senders, receivers, cnt, rcnt);
    k_scan2<<<2, 1024, 0, stream>>>(cnt, row_ptr, cursor,
                                    rcnt, rrow_ptr, rcur, out);
    k_scatter2<<<grid_e, b256, 0, stream>>>(senders, receivers, cursor, rcur,
                                            eids, rpos);
    k_permute<<<grid_e16, b256, 0, stream>>>(edge_features, eids, efp);

    float* hin = hidA;
    float* hout = hidB;
    for (int it = 0; it < 3; ++it) {
        k_msg<<<grid_n16, b256, 0, stream>>>(hin, efp,
                                             W_edge, b_edge, row_ptr, tmp);
        k_gru<<<grid_n16, b256, 0, stream>>>(hin, tmp, rrow_ptr, rpos,
                                             Wi_gru, Wh_gru, bi_gru, bh_gru, hout);
        float* t = hin; hin = hout; hout = t;
    }

    k_readout<<<grid_n, b256, 0, stream>>>(hin, hidden0, W_ri, b_ri, W_rj, b_rj, out);
}

// Round 8
// 426.857 us; speedup vs baseline: 1.8407x; 1.1639x over previous
//
#include <hip/hip_runtime.h>

#define N_NODES 25000
#define N_EDGES 400000

// ---------------- fast transcendentals (fp32, ~2ulp) ----------------
__device__ __forceinline__ float fast_sigmoid(float x) {
    return __builtin_amdgcn_rcpf(1.0f + __expf(-x));
}
__device__ __forceinline__ float fast_tanh(float x) {
    return 1.0f - 2.0f * __builtin_amdgcn_rcpf(__expf(2.0f * x) + 1.0f);
}

// lane j receives value from lane j^k within its 32-lane half (k<16 keeps it
// inside the 16-lane node group). BitMode offset = (xor<<10)|(or<<5)|and.
#define SWZF(x, k) __int_as_float(__builtin_amdgcn_ds_swizzle(__float_as_int(x), ((k) << 10) | 0x1F))
// broadcast lane t of each 16-lane group: src = (lane & 0x10) | t
#define BCAST16(x, t) __int_as_float(__builtin_amdgcn_ds_swizzle(__float_as_int(x), ((t) << 5) | 0x10))

// ---------------- K1: hidden0 = nf @ W_init + b_init ; copy; zero cnt/rcnt ---
__global__ void __launch_bounds__(256) k_init(
        const float* __restrict__ nf, const float* __restrict__ Wini,
        const float* __restrict__ bini,
        float* __restrict__ hidden0, float* __restrict__ hid,
        int* __restrict__ cnt, int* __restrict__ rcnt)
{
    int gtid = blockIdx.x * 256 + threadIdx.x;
    if (gtid <= N_NODES) { cnt[gtid] = 0; rcnt[gtid] = 0; }
    int node = gtid >> 4;
    int j = gtid & 15;
    if (node >= N_NODES) return;

    const float4* nf4 = (const float4*)(nf + node * 32);
    float acc = bini[j];
#pragma unroll
    for (int g = 0; g < 8; ++g) {
        float4 v = nf4[g];
        acc = fmaf(v.x, Wini[(g*4+0)*16 + j], acc);
        acc = fmaf(v.y, Wini[(g*4+1)*16 + j], acc);
        acc = fmaf(v.z, Wini[(g*4+2)*16 + j], acc);
        acc = fmaf(v.w, Wini[(g*4+3)*16 + j], acc);
    }
    hidden0[node*16 + j] = acc;
    hid[node*16 + j] = acc;
}

// ---------------- K2a: rank pass (histogram + within-bucket rank, 1 atomic
// round instead of 2; ranks stored streaming) ----------------
__global__ void __launch_bounds__(256) k_rank(const int* __restrict__ send,
        const int* __restrict__ recv,
        int* __restrict__ cnt, int* __restrict__ rcnt,
        int* __restrict__ rank_s, int* __restrict__ rank_r)
{
    int e = blockIdx.x * 256 + threadIdx.x;
    if (e < N_EDGES) {
        rank_s[e] = atomicAdd(&cnt[send[e]], 1);
        rank_r[e] = atomicAdd(&rcnt[recv[e]], 1);
    }
}

// Two independent exclusive scans, one per block (LDS-staged, coalesced I/O).
#define SCAN_TOT 25600                      // 1024 * 25
__global__ void __launch_bounds__(1024) k_scan2(
        const int* __restrict__ cnt,  int* __restrict__ row_ptr,
        const int* __restrict__ rcnt, int* __restrict__ rrow_ptr,
        float* __restrict__ out)
{
    __shared__ int data[SCAN_TOT];          // 100 KB
    __shared__ int sums[1024];              // 4 KB
    int t = threadIdx.x;
    const int CH = 25;

    const int* SRC = blockIdx.x ? rcnt : cnt;
    int* DST = blockIdx.x ? rrow_ptr : row_ptr;

    for (int i = t; i < SCAN_TOT; i += 1024)
        data[i] = (i < N_NODES) ? SRC[i] : 0;
    __syncthreads();

    int base = t * CH;
    int s = 0;
#pragma unroll
    for (int i = 0; i < CH; ++i) s += data[base + i];
    sums[t] = s;
    __syncthreads();

    for (int off = 1; off < 1024; off <<= 1) {
        int add = (t >= off) ? sums[t - off] : 0;
        __syncthreads();
        sums[t] += add;
        __syncthreads();
    }
    int run = sums[t] - s;

#pragma unroll
    for (int i = 0; i < CH; ++i) {
        int v = data[base + i];
        data[base + i] = run;
        run += v;
    }
    __syncthreads();

    for (int i = t; i < N_NODES; i += 1024)
        DST[i] = data[i];
    if (t == 0) {
        if (blockIdx.x == 0) { row_ptr[N_NODES] = N_EDGES; out[0] = 0.0f; }
        else                 { rrow_ptr[N_NODES] = N_EDGES; }
    }
}

// ---------------- K2b: placement pass, ZERO atomics ----------------
// pos = row_ptr[send] + rank_s; eids[pos] = e (sender-CSR).
// p = rrow_ptr[recv] + rank_r; rpos[p] = pos (receiver-CSR over sender pos).
// Scattered 4B stores into small L2-resident arrays; fire-and-forget.
__global__ void __launch_bounds__(256) k_place(const int* __restrict__ send,
        const int* __restrict__ recv,
        const int* __restrict__ rank_s, const int* __restrict__ rank_r,
        const int* __restrict__ row_ptr, const int* __restrict__ rrow_ptr,
        int* __restrict__ eids, int* __restrict__ rpos)
{
    int e = blockIdx.x * 256 + threadIdx.x;
    if (e < N_EDGES) {
        int pos = row_ptr[send[e]] + rank_s[e];
        eids[pos] = e;
        rpos[rrow_ptr[recv[e]] + rank_r[e]] = pos;
    }
}

// efp[pos,:] = ef[eids[pos],:]  (edge features into sender-CSR order; once)
__global__ void __launch_bounds__(256) k_permute(const float* __restrict__ ef,
        const int* __restrict__ eids, float* __restrict__ efp)
{
    int gtid = blockIdx.x * 256 + threadIdx.x;
    int pos = gtid >> 4;
    int c = gtid & 15;
    if (pos < N_EDGES) efp[(size_t)pos*16 + c] = ef[(size_t)eids[pos]*16 + c];
}

// ---------------- K3: 16 senders per block, efp staged through LDS ----------
// Block = 16 groups; group g = sender blockIdx*16+g; the 16 senders' edges are
// CONTIGUOUS in efp (sender-CSR). Chunked: cooperatively load up to 512 edges
// (32 KB) into LDS with per-lane-distinct coalesced loads, then groups read
// their edges from LDS where same-address broadcast is free. This removes the
// 16x L1 broadcast redundancy that bounded the previous version (~400 MB of
// L1 traffic -> ~25 MB global + cheap LDS).
#define MCHUNK 512
#define MSG16(E0,E1,E2,E3) ( \
    ( fmaf((E0).w,q[3],  fmaf((E0).z,q[2],  fmaf((E0).y,q[1],  fmaf((E0).x,q[0],  qb)))) \
    + fmaf((E1).w,q[7],  fmaf((E1).z,q[6],  fmaf((E1).y,q[5],  fmaf((E1).x,q[4],  0.0f)))) ) \
  + ( fmaf((E2).w,q[11], fmaf((E2).z,q[10], fmaf((E2).y,q[9],  fmaf((E2).x,q[8],  0.0f)))) \
    + fmaf((E3).w,q[15], fmaf((E3).z,q[14], fmaf((E3).y,q[13], fmaf((E3).x,q[12], 0.0f)))) ) )

__global__ void __launch_bounds__(256) k_msg(
        const float* __restrict__ hid, const float* __restrict__ efp,
        const float* __restrict__ We, const float* __restrict__ be,
        const int* __restrict__ row_ptr,
        float* __restrict__ tmp)
{
    __shared__ float sef[MCHUNK * 16];          // 32 KB
    int tid = threadIdx.x;
    int grp = tid >> 4;
    int m   = tid & 15;
    int s   = blockIdx.x * 16 + grp;
    bool active = (s < N_NODES);
    int sc = active ? s : 0;

    int s0 = blockIdx.x * 16;                   // < N_NODES always (1563*16=25008, s0<=24992)
    int blk_beg = row_ptr[s0];
    int s1 = s0 + 16; if (s1 > N_NODES) s1 = N_NODES;
    int blk_end = row_ptr[s1];

    int beg = active ? row_ptr[s]     : 0;
    int end = active ? row_ptr[s + 1] : 0;

    float h[16];
    {
        const float4* h4 = (const float4*)(hid + sc*16);
        float4 a = h4[0], b = h4[1], c = h4[2], d = h4[3];
        h[0]=a.x; h[1]=a.y; h[2]=a.z;  h[3]=a.w;
        h[4]=b.x; h[5]=b.y; h[6]=b.z;  h[7]=b.w;
        h[8]=c.x; h[9]=c.y; h[10]=c.z; h[11]=c.w;
        h[12]=d.x; h[13]=d.y; h[14]=d.z; h[15]=d.w;
    }
    float q[16];
#pragma unroll
    for (int f = 0; f < 16; ++f) {
        const float4* wf = (const float4*)(We + f*256 + m*16);
        float4 a = wf[0], b = wf[1], c = wf[2], d = wf[3];
        float acc;
        acc  = a.x*h[0]  + a.y*h[1]  + a.z*h[2]  + a.w*h[3];
        acc += b.x*h[4]  + b.y*h[5]  + b.z*h[6]  + b.w*h[7];
        acc += c.x*h[8]  + c.y*h[9]  + c.z*h[10] + c.w*h[11];
        acc += d.x*h[12] + d.y*h[13] + d.z*h[14] + d.w*h[15];
        q[f] = acc;
    }
    float qb;
    {
        const float4* bf = (const float4*)(be + m*16);
        float4 a = bf[0], b = bf[1], c = bf[2], d = bf[3];
        qb  = a.x*h[0]  + a.y*h[1]  + a.z*h[2]  + a.w*h[3];
        qb += b.x*h[4]  + b.y*h[5]  + b.z*h[6]  + b.w*h[7];
        qb += c.x*h[8]  + c.y*h[9]  + c.z*h[10] + c.w*h[11];
        qb += d.x*h[12] + d.y*h[13] + d.z*h[14] + d.w*h[15];
    }

    for (int cbeg = blk_beg; cbeg < blk_end; cbeg += MCHUNK) {
        int cend = cbeg + MCHUNK; if (cend > blk_end) cend = blk_end;
        int nfl = (cend - cbeg) * 4;            // float4 count to stage
        __syncthreads();                        // protect prev chunk's readers
        {
            const float4* gsrc = (const float4*)(efp + (size_t)cbeg * 16);
            float4* ldst = (float4*)sef;
            for (int i = tid; i < nfl; i += 256) ldst[i] = gsrc[i];
        }
        __syncthreads();

        int lo = beg > cbeg ? beg : cbeg;
        int hi = end < cend ? end : cend;
        int i = lo;
        for (; i + 2 <= hi; i += 2) {
            const float4* l0 = (const float4*)(sef + (size_t)(i   - cbeg) * 16);
            const float4* l1 = (const float4*)(sef + (size_t)(i+1 - cbeg) * 16);
            float4 A0=l0[0], A1=l0[1], A2=l0[2], A3=l0[3];
            float4 B0=l1[0], B1=l1[1], B2=l1[2], B3=l1[3];
            float v0 = MSG16(A0, A1, A2, A3);
            float v1 = MSG16(B0, B1, B2, B3);
            tmp[(size_t)(i+0)*16 + m] = v0;
            tmp[(size_t)(i+1)*16 + m] = v1;
        }
        for (; i < hi; ++i) {
            const float4* l0 = (const float4*)(sef + (size_t)(i - cbeg) * 16);
            float4 A0=l0[0], A1=l0[1], A2=l0[2], A3=l0[3];
            tmp[(size_t)i*16 + m] = MSG16(A0, A1, A2, A3);
        }
    }
}

// ---------------- K4: line-gather + GRU (T=32), 2 scalars/lane ---------------
__global__ void __launch_bounds__(256) k_gru(
        const float* __restrict__ hid_in, const float* __restrict__ tmp,
        const int* __restrict__ rrow_ptr, const int* __restrict__ rpos,
        const float* __restrict__ Wi, const float* __restrict__ Wh,
        const float* __restrict__ bi, const float* __restrict__ bh,
        float* __restrict__ hid_out)
{
    int gtid = blockIdx.x * 256 + threadIdx.x;
    int node = gtid >> 4;
    int j = gtid & 15;
    if (node >= N_NODES) return;

    float s0 = 0.0f, s1 = 0.0f, s2 = 0.0f, s3 = 0.0f;
    {
        int beg = rrow_ptr[node];
        int end = rrow_ptr[node + 1];
        int d = end - beg;
        int i = 0;
        for (; i + 8 <= d; i += 8) {
            int p0 = rpos[beg + i + 0];
            int p1 = rpos[beg + i + 1];
            int p2 = rpos[beg + i + 2];
            int p3 = rpos[beg + i + 3];
            int p4 = rpos[beg + i + 4];
            int p5 = rpos[beg + i + 5];
            int p6 = rpos[beg + i + 6];
            int p7 = rpos[beg + i + 7];
            float a0 = tmp[(size_t)p0*16 + j];
            float a1 = tmp[(size_t)p1*16 + j];
            float a2 = tmp[(size_t)p2*16 + j];
            float a3 = tmp[(size_t)p3*16 + j];
            float a4 = tmp[(size_t)p4*16 + j];
            float a5 = tmp[(size_t)p5*16 + j];
            float a6 = tmp[(size_t)p6*16 + j];
            float a7 = tmp[(size_t)p7*16 + j];
            s0 += a0; s1 += a1; s2 += a2; s3 += a3;
            s0 += a4; s1 += a5; s2 += a6; s3 += a7;
        }
        for (; i < d; ++i) s0 += tmp[(size_t)rpos[beg + i]*16 + j];
    }
    float msg_own = (s0 + s1) + (s2 + s3);
    float h_own = hid_in[node*16 + j];

    float Wz[16], Wr[16], Wc[16];
#pragma unroll
    for (int k = 0; k < 16; ++k) {
        int l = j ^ k;
        Wz[k] = Wh[l*48 + j];
        Wr[k] = Wh[l*48 + 16 + j];
        Wc[k] = Wh[l*48 + 32 + j];
    }
    float Wiz = Wi[j], Wir = Wi[16+j], Wih = Wi[32+j];
    float cz   = bi[j] + bh[j];
    float cr   = bi[16+j] + bh[16+j];
    float bih_ = bi[32+j];
    float bhh_ = bh[32+j];

    float hn = 0.0f;

#define STEPK(k) { float v = SWZF(hn, k); \
        az = fmaf(v, Wz[k], az); ar = fmaf(v, Wr[k], ar); ac = fmaf(v, Wc[k], ac); }

#define GRUSTEP(XV) { \
        float xv = (XV); \
        float az = fmaf(xv, Wiz, cz); \
        float ar = fmaf(xv, Wir, cr); \
        float ac = bhh_; \
        az = fmaf(hn, Wz[0], az); \
        ar = fmaf(hn, Wr[0], ar); \
        ac = fmaf(hn, Wc[0], ac); \
        STEPK(1)  STEPK(2)  STEPK(3)  STEPK(4)  STEPK(5) \
        STEPK(6)  STEPK(7)  STEPK(8)  STEPK(9)  STEPK(10) \
        STEPK(11) STEPK(12) STEPK(13) STEPK(14) STEPK(15) \
        float z  = fast_sigmoid(az); \
        float r  = fast_sigmoid(ar); \
        float hc = fast_tanh(fmaf(xv, Wih, bih_) + r * ac); \
        hn = fmaf(z, hn - hc, hc); }

    // t = 0..15: x_t = hidden[node][t]
    GRUSTEP(BCAST16(h_own, 0))  GRUSTEP(BCAST16(h_own, 1))
    GRUSTEP(BCAST16(h_own, 2))  GRUSTEP(BCAST16(h_own, 3))
    GRUSTEP(BCAST16(h_own, 4))  GRUSTEP(BCAST16(h_own, 5))
    GRUSTEP(BCAST16(h_own, 6))  GRUSTEP(BCAST16(h_own, 7))
    GRUSTEP(BCAST16(h_own, 8))  GRUSTEP(BCAST16(h_own, 9))
    GRUSTEP(BCAST16(h_own, 10)) GRUSTEP(BCAST16(h_own, 11))
    GRUSTEP(BCAST16(h_own, 12)) GRUSTEP(BCAST16(h_own, 13))
    GRUSTEP(BCAST16(h_own, 14)) GRUSTEP(BCAST16(h_own, 15))
    // t = 16..31: x_t = messages[node][t-16]
    GRUSTEP(BCAST16(msg_own, 0))  GRUSTEP(BCAST16(msg_own, 1))
    GRUSTEP(BCAST16(msg_own, 2))  GRUSTEP(BCAST16(msg_own, 3))
    GRUSTEP(BCAST16(msg_own, 4))  GRUSTEP(BCAST16(msg_own, 5))
    GRUSTEP(BCAST16(msg_own, 6))  GRUSTEP(BCAST16(msg_own, 7))
    GRUSTEP(BCAST16(msg_own, 8))  GRUSTEP(BCAST16(msg_own, 9))
    GRUSTEP(BCAST16(msg_own, 10)) GRUSTEP(BCAST16(msg_own, 11))
    GRUSTEP(BCAST16(msg_own, 12)) GRUSTEP(BCAST16(msg_own, 13))
    GRUSTEP(BCAST16(msg_own, 14)) GRUSTEP(BCAST16(msg_own, 15))
#undef GRUSTEP
#undef STEPK

    hid_out[node*16 + j] = hn;
}

// ---------------- K5: readout ----------------
__global__ void __launch_bounds__(256) k_readout(
        const float* __restrict__ hid, const float* __restrict__ hid0,
        const float* __restrict__ Wri, const float* __restrict__ bri,
        const float* __restrict__ Wrj, const float* __restrict__ brj,
        float* __restrict__ out)
{
    int n = blockIdx.x * 256 + threadIdx.x;
    float val = 0.0f;
    if (n < N_NODES) {
        const float4* h4 = (const float4*)(hid + n * 16);
        const float4* g4 = (const float4*)(hid0 + n * 16);
        float iv = bri[0];
        float jv = brj[0];
#pragma unroll
        for (int g = 0; g < 4; ++g) {
            float4 h  = h4[g];
            float4 h0 = g4[g];
            iv = fmaf(h.x,  Wri[g*4+0], iv);  iv = fmaf(h.y,  Wri[g*4+1], iv);
            iv = fmaf(h.z,  Wri[g*4+2], iv);  iv = fmaf(h.w,  Wri[g*4+3], iv);
            iv = fmaf(h0.x, Wri[16+g*4+0], iv); iv = fmaf(h0.y, Wri[16+g*4+1], iv);
            iv = fmaf(h0.z, Wri[16+g*4+2], iv); iv = fmaf(h0.w, Wri[16+g*4+3], iv);
            jv = fmaf(h.x,  Wrj[g*4+0], jv);  jv = fmaf(h.y,  Wrj[g*4+1], jv);
            jv = fmaf(h.z,  Wrj[g*4+2], jv);  jv = fmaf(h.w,  Wrj[g*4+3], jv);
        }
        val = iv * jv;
    }
#pragma unroll
    for (int off = 32; off > 0; off >>= 1)
        val += __shfl_xor(val, off, 64);
    __shared__ float wsum[4];
    int w = threadIdx.x >> 6;
    if ((threadIdx.x & 63) == 0) wsum[w] = val;
    __syncthreads();
    if (threadIdx.x == 0)
        atomicAdd(out, wsum[0] + wsum[1] + wsum[2] + wsum[3]);
}

// ---------------- launch ----------------
extern "C" void kernel_launch(void* const* d_in, const int* in_sizes, int n_in,
                              void* d_out, int out_size, void* d_ws, size_t ws_size,
                              hipStream_t stream)
{
    const float* node_features = (const float*)d_in[0];
    const float* edge_features = (const float*)d_in[1];
    const float* W_init = (const float*)d_in[2];
    const float* b_init = (const float*)d_in[3];
    const float* W_edge = (const float*)d_in[4];
    const float* b_edge = (const float*)d_in[5];
    const float* Wi_gru = (const float*)d_in[6];
    const float* Wh_gru = (const float*)d_in[7];
    const float* bi_gru = (const float*)d_in[8];
    const float* bh_gru = (const float*)d_in[9];
    const float* W_ri = (const float*)d_in[10];
    const float* b_ri = (const float*)d_in[11];
    const float* W_rj = (const float*)d_in[12];
    const float* b_rj = (const float*)d_in[13];
    const int* receivers = (const int*)d_in[14];
    const int* senders   = (const int*)d_in[15];
    float* out = (float*)d_out;

    // workspace carve: floats then ints; ~63 MB total
    float* fb      = (float*)d_ws;
    float* hidden0 = fb;                 // 400000
    float* hidA    = fb + 400000;        // 400000
    float* hidB    = fb + 800000;        // 400000
    float* tmp     = fb + 1200000;       // 6400000 (E*16, sender-order msgs)
    float* efp     = fb + 7600000;       // 6400000 (E*16, sender-order feats)
    int* ib       = (int*)(fb + 14000000);
    int* cnt      = ib;                  // 25024
    int* row_ptr  = ib + 25024;          // 25024
    int* rcnt     = ib + 50048;          // 25024
    int* rrow_ptr = ib + 75072;          // 25024
    int* eids     = ib + 100096;         // 400000
    int* rpos     = ib + 500096;         // 400000
    int* rank_s   = ib + 900096;         // 400000
    int* rank_r   = ib + 1300096;        // 400000

    dim3 b256(256);
    int grid_n16 = (N_NODES * 16 + 255) / 256;   // 1563
    int grid_e   = (N_EDGES + 255) / 256;        // 1563
    int grid_e16 = (N_EDGES * 16 + 255) / 256;   // 25000
    int grid_n   = (N_NODES + 255) / 256;        // 98
    int grid_blk = (N_NODES + 15) / 16;          // 1563 (16 senders per block)

    k_init<<<grid_n16, b256, 0, stream>>>(node_features, W_init, b_init,
                                          hidden0, hidA, cnt, rcnt);
    k_rank<<<grid_e, b256, 0, stream>>>(senders, receivers, cnt, rcnt,
                                        rank_s, rank_r);
    k_scan2<<<2, 1024, 0, stream>>>(cnt, row_ptr, rcnt, rrow_ptr, out);
    k_place<<<grid_e, b256, 0, stream>>>(senders, receivers, rank_s, rank_r,
                                         row_ptr, rrow_ptr, eids, rpos);
    k_permute<<<grid_e16, b256, 0, stream>>>(edge_features, eids, efp);

    float* hin = hidA;
    float* hout = hidB;
    for (int it = 0; it < 3; ++it) {
        k_msg<<<grid_blk, b256, 0, stream>>>(hin, efp,
                                             W_edge, b_edge, row_ptr, tmp);
        k_gru<<<grid_n16, b256, 0, stream>>>(hin, tmp, rrow_ptr, rpos,
                                             Wi_gru, Wh_gru, bi_gru, bh_gru, hout);
        float* t = hin; hin = hout; hout = t;
    }

    k_readout<<<grid_n, b256, 0, stream>>>(hin, hidden0, W_ri, b_ri, W_rj, b_rj, out);
}

// Round 9
// 405.301 us; speedup vs baseline: 1.9386x; 1.0532x over previous
//
#include <hip/hip_runtime.h>

#define N_NODES 25000
#define N_EDGES 400000

// ---------------- fast transcendentals (fp32, ~2ulp) ----------------
__device__ __forceinline__ float fast_sigmoid(float x) {
    return __builtin_amdgcn_rcpf(1.0f + __expf(-x));
}
__device__ __forceinline__ float fast_tanh(float x) {
    return 1.0f - 2.0f * __builtin_amdgcn_rcpf(__expf(2.0f * x) + 1.0f);
}

// lane j receives value from lane j^k within its 32-lane half (k<16 keeps it
// inside the 16-lane node group). BitMode offset = (xor<<10)|(or<<5)|and.
#define SWZF(x, k) __int_as_float(__builtin_amdgcn_ds_swizzle(__float_as_int(x), ((k) << 10) | 0x1F))
// broadcast lane t of each 16-lane group: src = (lane & 0x10) | t
#define BCAST16(x, t) __int_as_float(__builtin_amdgcn_ds_swizzle(__float_as_int(x), ((t) << 5) | 0x10))

// ---------------- K1: hidden0 = nf @ W_init + b_init ; copy; zero cnt/rcnt ---
__global__ void __launch_bounds__(256) k_init(
        const float* __restrict__ nf, const float* __restrict__ Wini,
        const float* __restrict__ bini,
        float* __restrict__ hidden0, float* __restrict__ hid,
        int* __restrict__ cnt, int* __restrict__ rcnt)
{
    int gtid = blockIdx.x * 256 + threadIdx.x;
    if (gtid <= N_NODES) { cnt[gtid] = 0; rcnt[gtid] = 0; }
    int node = gtid >> 4;
    int j = gtid & 15;
    if (node >= N_NODES) return;

    const float4* nf4 = (const float4*)(nf + node * 32);
    float acc = bini[j];
#pragma unroll
    for (int g = 0; g < 8; ++g) {
        float4 v = nf4[g];
        acc = fmaf(v.x, Wini[(g*4+0)*16 + j], acc);
        acc = fmaf(v.y, Wini[(g*4+1)*16 + j], acc);
        acc = fmaf(v.z, Wini[(g*4+2)*16 + j], acc);
        acc = fmaf(v.w, Wini[(g*4+3)*16 + j], acc);
    }
    hidden0[node*16 + j] = acc;
    hid[node*16 + j] = acc;
}

// ---------------- K2a: rank pass (histogram + within-bucket rank) ----------
__global__ void __launch_bounds__(256) k_rank(const int* __restrict__ send,
        const int* __restrict__ recv,
        int* __restrict__ cnt, int* __restrict__ rcnt,
        int* __restrict__ rank_s, int* __restrict__ rank_r)
{
    int e = blockIdx.x * 256 + threadIdx.x;
    if (e < N_EDGES) {
        rank_s[e] = atomicAdd(&cnt[send[e]], 1);
        rank_r[e] = atomicAdd(&rcnt[recv[e]], 1);
    }
}

// Two independent exclusive scans, one per block (LDS-staged, coalesced I/O).
#define SCAN_TOT 25600                      // 1024 * 25
__global__ void __launch_bounds__(1024) k_scan2(
        const int* __restrict__ cnt,  int* __restrict__ row_ptr,
        const int* __restrict__ rcnt, int* __restrict__ rrow_ptr,
        float* __restrict__ out)
{
    __shared__ int data[SCAN_TOT];          // 100 KB
    __shared__ int sums[1024];              // 4 KB
    int t = threadIdx.x;
    const int CH = 25;

    const int* SRC = blockIdx.x ? rcnt : cnt;
    int* DST = blockIdx.x ? rrow_ptr : row_ptr;

    for (int i = t; i < SCAN_TOT; i += 1024)
        data[i] = (i < N_NODES) ? SRC[i] : 0;
    __syncthreads();

    int base = t * CH;
    int s = 0;
#pragma unroll
    for (int i = 0; i < CH; ++i) s += data[base + i];
    sums[t] = s;
    __syncthreads();

    for (int off = 1; off < 1024; off <<= 1) {
        int add = (t >= off) ? sums[t - off] : 0;
        __syncthreads();
        sums[t] += add;
        __syncthreads();
    }
    int run = sums[t] - s;

#pragma unroll
    for (int i = 0; i < CH; ++i) {
        int v = data[base + i];
        data[base + i] = run;
        run += v;
    }
    __syncthreads();

    for (int i = t; i < N_NODES; i += 1024)
        DST[i] = data[i];
    if (t == 0) {
        if (blockIdx.x == 0) { row_ptr[N_NODES] = N_EDGES; out[0] = 0.0f; }
        else                 { rrow_ptr[N_NODES] = N_EDGES; }
    }
}

// ---------------- K2b: placement pass, ZERO atomics ----------------
// pos = row_ptr[send]+rank_s  (sender-CSR slot of edge e)
// p   = rrow_ptr[recv]+rank_r (receiver-CSR slot of edge e)
// ipos[e]  = pos  (coalesced)  -> used by k_permute (seq read, scatter store)
// rp[pos]  = p    (scattered)  -> used by k_msg to store msgs receiver-ordered
__global__ void __launch_bounds__(256) k_place(const int* __restrict__ send,
        const int* __restrict__ recv,
        const int* __restrict__ rank_s, const int* __restrict__ rank_r,
        const int* __restrict__ row_ptr, const int* __restrict__ rrow_ptr,
        int* __restrict__ ipos, int* __restrict__ rp)
{
    int e = blockIdx.x * 256 + threadIdx.x;
    if (e < N_EDGES) {
        int pos = row_ptr[send[e]] + rank_s[e];
        ipos[e] = pos;
        rp[pos] = rrow_ptr[recv[e]] + rank_r[e];
    }
}

// ---------------- K2c: edge features -> sender-CSR order (scatter form) -----
// Sequential read of ef (coalesced), scattered full-line store via ipos.
// (Scatter-writes are fire-and-forget; the old gather form stalled on random
// dependent reads.)
__global__ void __launch_bounds__(256) k_permute(const float* __restrict__ ef,
        const int* __restrict__ ipos, float* __restrict__ efp)
{
    int gtid = blockIdx.x * 256 + threadIdx.x;
    int e = gtid >> 4;
    int c = gtid & 15;
    if (e < N_EDGES) efp[(size_t)ipos[e]*16 + c] = ef[(size_t)e*16 + c];
}

// ---------------- K3: 16 senders per block, efp staged through LDS,
// messages scatter-stored in RECEIVER order (rp) ----------
#define MCHUNK 512
#define MSG16(E0,E1,E2,E3) ( \
    ( fmaf((E0).w,q[3],  fmaf((E0).z,q[2],  fmaf((E0).y,q[1],  fmaf((E0).x,q[0],  qb)))) \
    + fmaf((E1).w,q[7],  fmaf((E1).z,q[6],  fmaf((E1).y,q[5],  fmaf((E1).x,q[4],  0.0f)))) ) \
  + ( fmaf((E2).w,q[11], fmaf((E2).z,q[10], fmaf((E2).y,q[9],  fmaf((E2).x,q[8],  0.0f)))) \
    + fmaf((E3).w,q[15], fmaf((E3).z,q[14], fmaf((E3).y,q[13], fmaf((E3).x,q[12], 0.0f)))) ) )

__global__ void __launch_bounds__(256) k_msg(
        const float* __restrict__ hid, const float* __restrict__ efp,
        const int* __restrict__ rp,
        const float* __restrict__ We, const float* __restrict__ be,
        const int* __restrict__ row_ptr,
        float* __restrict__ tmp)
{
    __shared__ float sef[MCHUNK * 16];          // 32 KB
    __shared__ int   srp[MCHUNK];               // 2 KB
    int tid = threadIdx.x;
    int grp = tid >> 4;
    int m   = tid & 15;
    int s   = blockIdx.x * 16 + grp;
    bool active = (s < N_NODES);
    int sc = active ? s : 0;

    int s0 = blockIdx.x * 16;
    int blk_beg = row_ptr[s0];
    int s1 = s0 + 16; if (s1 > N_NODES) s1 = N_NODES;
    int blk_end = row_ptr[s1];

    int beg = active ? row_ptr[s]     : 0;
    int end = active ? row_ptr[s + 1] : 0;

    float h[16];
    {
        const float4* h4 = (const float4*)(hid + sc*16);
        float4 a = h4[0], b = h4[1], c = h4[2], d = h4[3];
        h[0]=a.x; h[1]=a.y; h[2]=a.z;  h[3]=a.w;
        h[4]=b.x; h[5]=b.y; h[6]=b.z;  h[7]=b.w;
        h[8]=c.x; h[9]=c.y; h[10]=c.z; h[11]=c.w;
        h[12]=d.x; h[13]=d.y; h[14]=d.z; h[15]=d.w;
    }
    float q[16];
#pragma unroll
    for (int f = 0; f < 16; ++f) {
        const float4* wf = (const float4*)(We + f*256 + m*16);
        float4 a = wf[0], b = wf[1], c = wf[2], d = wf[3];
        float acc;
        acc  = a.x*h[0]  + a.y*h[1]  + a.z*h[2]  + a.w*h[3];
        acc += b.x*h[4]  + b.y*h[5]  + b.z*h[6]  + b.w*h[7];
        acc += c.x*h[8]  + c.y*h[9]  + c.z*h[10] + c.w*h[11];
        acc += d.x*h[12] + d.y*h[13] + d.z*h[14] + d.w*h[15];
        q[f] = acc;
    }
    float qb;
    {
        const float4* bf = (const float4*)(be + m*16);
        float4 a = bf[0], b = bf[1], c = bf[2], d = bf[3];
        qb  = a.x*h[0]  + a.y*h[1]  + a.z*h[2]  + a.w*h[3];
        qb += b.x*h[4]  + b.y*h[5]  + b.z*h[6]  + b.w*h[7];
        qb += c.x*h[8]  + c.y*h[9]  + c.z*h[10] + c.w*h[11];
        qb += d.x*h[12] + d.y*h[13] + d.z*h[14] + d.w*h[15];
    }

    for (int cbeg = blk_beg; cbeg < blk_end; cbeg += MCHUNK) {
        int cend = cbeg + MCHUNK; if (cend > blk_end) cend = blk_end;
        int nedge = cend - cbeg;
        int nfl = nedge * 4;
        __syncthreads();
        {
            const float4* gsrc = (const float4*)(efp + (size_t)cbeg * 16);
            float4* ldst = (float4*)sef;
            for (int i = tid; i < nfl; i += 256) ldst[i] = gsrc[i];
            for (int i = tid; i < nedge; i += 256) srp[i] = rp[cbeg + i];
        }
        __syncthreads();

        int lo = beg > cbeg ? beg : cbeg;
        int hi = end < cend ? end : cend;
        int i = lo;
        for (; i + 2 <= hi; i += 2) {
            const float4* l0 = (const float4*)(sef + (size_t)(i   - cbeg) * 16);
            const float4* l1 = (const float4*)(sef + (size_t)(i+1 - cbeg) * 16);
            float4 A0=l0[0], A1=l0[1], A2=l0[2], A3=l0[3];
            float4 B0=l1[0], B1=l1[1], B2=l1[2], B3=l1[3];
            int r0 = srp[i   - cbeg];
            int r1 = srp[i+1 - cbeg];
            float v0 = MSG16(A0, A1, A2, A3);
            float v1 = MSG16(B0, B1, B2, B3);
            tmp[(size_t)r0*16 + m] = v0;
            tmp[(size_t)r1*16 + m] = v1;
        }
        for (; i < hi; ++i) {
            const float4* l0 = (const float4*)(sef + (size_t)(i - cbeg) * 16);
            float4 A0=l0[0], A1=l0[1], A2=l0[2], A3=l0[3];
            int r0 = srp[i - cbeg];
            tmp[(size_t)r0*16 + m] = MSG16(A0, A1, A2, A3);
        }
    }
}

// ---------------- K4: STREAMING gather + GRU (T=32), 2 scalars/lane ---------
// tmp is receiver-CSR ordered: node's in-edge messages are CONTIGUOUS.
// Lane j reads dword j of consecutive 64B lines -- zero indirection, addresses
// known upfront, unroll x8 with 4 accumulators. Whole-wave access pattern is
// near-sequential across the kernel.
__global__ void __launch_bounds__(256) k_gru(
        const float* __restrict__ hid_in, const float* __restrict__ tmp,
        const int* __restrict__ rrow_ptr,
        const float* __restrict__ Wi, const float* __restrict__ Wh,
        const float* __restrict__ bi, const float* __restrict__ bh,
        float* __restrict__ hid_out)
{
    int gtid = blockIdx.x * 256 + threadIdx.x;
    int node = gtid >> 4;
    int j = gtid & 15;
    if (node >= N_NODES) return;

    float s0 = 0.0f, s1 = 0.0f, s2 = 0.0f, s3 = 0.0f;
    {
        int beg = rrow_ptr[node];
        int end = rrow_ptr[node + 1];
        const float* p = tmp + (size_t)beg * 16 + j;
        int d = end - beg;
        int i = 0;
        for (; i + 8 <= d; i += 8) {
            float a0 = p[(i+0)*16];
            float a1 = p[(i+1)*16];
            float a2 = p[(i+2)*16];
            float a3 = p[(i+3)*16];
            float a4 = p[(i+4)*16];
            float a5 = p[(i+5)*16];
            float a6 = p[(i+6)*16];
            float a7 = p[(i+7)*16];
            s0 += a0; s1 += a1; s2 += a2; s3 += a3;
            s0 += a4; s1 += a5; s2 += a6; s3 += a7;
        }
        for (; i < d; ++i) s0 += p[i*16];
    }
    float msg_own = (s0 + s1) + (s2 + s3);
    float h_own = hid_in[node*16 + j];

    float Wz[16], Wr[16], Wc[16];
#pragma unroll
    for (int k = 0; k < 16; ++k) {
        int l = j ^ k;
        Wz[k] = Wh[l*48 + j];
        Wr[k] = Wh[l*48 + 16 + j];
        Wc[k] = Wh[l*48 + 32 + j];
    }
    float Wiz = Wi[j], Wir = Wi[16+j], Wih = Wi[32+j];
    float cz   = bi[j] + bh[j];
    float cr   = bi[16+j] + bh[16+j];
    float bih_ = bi[32+j];
    float bhh_ = bh[32+j];

    float hn = 0.0f;

#define STEPK(k) { float v = SWZF(hn, k); \
        az = fmaf(v, Wz[k], az); ar = fmaf(v, Wr[k], ar); ac = fmaf(v, Wc[k], ac); }

#define GRUSTEP(XV) { \
        float xv = (XV); \
        float az = fmaf(xv, Wiz, cz); \
        float ar = fmaf(xv, Wir, cr); \
        float ac = bhh_; \
        az = fmaf(hn, Wz[0], az); \
        ar = fmaf(hn, Wr[0], ar); \
        ac = fmaf(hn, Wc[0], ac); \
        STEPK(1)  STEPK(2)  STEPK(3)  STEPK(4)  STEPK(5) \
        STEPK(6)  STEPK(7)  STEPK(8)  STEPK(9)  STEPK(10) \
        STEPK(11) STEPK(12) STEPK(13) STEPK(14) STEPK(15) \
        float z  = fast_sigmoid(az); \
        float r  = fast_sigmoid(ar); \
        float hc = fast_tanh(fmaf(xv, Wih, bih_) + r * ac); \
        hn = fmaf(z, hn - hc, hc); }

    // t = 0..15: x_t = hidden[node][t]
    GRUSTEP(BCAST16(h_own, 0))  GRUSTEP(BCAST16(h_own, 1))
    GRUSTEP(BCAST16(h_own, 2))  GRUSTEP(BCAST16(h_own, 3))
    GRUSTEP(BCAST16(h_own, 4))  GRUSTEP(BCAST16(h_own, 5))
    GRUSTEP(BCAST16(h_own, 6))  GRUSTEP(BCAST16(h_own, 7))
    GRUSTEP(BCAST16(h_own, 8))  GRUSTEP(BCAST16(h_own, 9))
    GRUSTEP(BCAST16(h_own, 10)) GRUSTEP(BCAST16(h_own, 11))
    GRUSTEP(BCAST16(h_own, 12)) GRUSTEP(BCAST16(h_own, 13))
    GRUSTEP(BCAST16(h_own, 14)) GRUSTEP(BCAST16(h_own, 15))
    // t = 16..31: x_t = messages[node][t-16]
    GRUSTEP(BCAST16(msg_own, 0))  GRUSTEP(BCAST16(msg_own, 1))
    GRUSTEP(BCAST16(msg_own, 2))  GRUSTEP(BCAST16(msg_own, 3))
    GRUSTEP(BCAST16(msg_own, 4))  GRUSTEP(BCAST16(msg_own, 5))
    GRUSTEP(BCAST16(msg_own, 6))  GRUSTEP(BCAST16(msg_own, 7))
    GRUSTEP(BCAST16(msg_own, 8))  GRUSTEP(BCAST16(msg_own, 9))
    GRUSTEP(BCAST16(msg_own, 10)) GRUSTEP(BCAST16(msg_own, 11))
    GRUSTEP(BCAST16(msg_own, 12)) GRUSTEP(BCAST16(msg_own, 13))
    GRUSTEP(BCAST16(msg_own, 14)) GRUSTEP(BCAST16(msg_own, 15))
#undef GRUSTEP
#undef STEPK

    hid_out[node*16 + j] = hn;
}

// ---------------- K5: readout ----------------
__global__ void __launch_bounds__(256) k_readout(
        const float* __restrict__ hid, const float* __restrict__ hid0,
        const float* __restrict__ Wri, const float* __restrict__ bri,
        const float* __restrict__ Wrj, const float* __restrict__ brj,
        float* __restrict__ out)
{
    int n = blockIdx.x * 256 + threadIdx.x;
    float val = 0.0f;
    if (n < N_NODES) {
        const float4* h4 = (const float4*)(hid + n * 16);
        const float4* g4 = (const float4*)(hid0 + n * 16);
        float iv = bri[0];
        float jv = brj[0];
#pragma unroll
        for (int g = 0; g < 4; ++g) {
            float4 h  = h4[g];
            float4 h0 = g4[g];
            iv = fmaf(h.x,  Wri[g*4+0], iv);  iv = fmaf(h.y,  Wri[g*4+1], iv);
            iv = fmaf(h.z,  Wri[g*4+2], iv);  iv = fmaf(h.w,  Wri[g*4+3], iv);
            iv = fmaf(h0.x, Wri[16+g*4+0], iv); iv = fmaf(h0.y, Wri[16+g*4+1], iv);
            iv = fmaf(h0.z, Wri[16+g*4+2], iv); iv = fmaf(h0.w, Wri[16+g*4+3], iv);
            jv = fmaf(h.x,  Wrj[g*4+0], jv);  jv = fmaf(h.y,  Wrj[g*4+1], jv);
            jv = fmaf(h.z,  Wrj[g*4+2], jv);  jv = fmaf(h.w,  Wrj[g*4+3], jv);
        }
        val = iv * jv;
    }
#pragma unroll
    for (int off = 32; off > 0; off >>= 1)
        val += __shfl_xor(val, off, 64);
    __shared__ float wsum[4];
    int w = threadIdx.x >> 6;
    if ((threadIdx.x & 63) == 0) wsum[w] = val;
    __syncthreads();
    if (threadIdx.x == 0)
        atomicAdd(out, wsum[0] + wsum[1] + wsum[2] + wsum[3]);
}

// ---------------- launch ----------------
extern "C" void kernel_launch(void* const* d_in, const int* in_sizes, int n_in,
                              void* d_out, int out_size, void* d_ws, size_t ws_size,
                              hipStream_t stream)
{
    const float* node_features = (const float*)d_in[0];
    const float* edge_features = (const float*)d_in[1];
    const float* W_init = (const float*)d_in[2];
    const float* b_init = (const float*)d_in[3];
    const float* W_edge = (const float*)d_in[4];
    const float* b_edge = (const float*)d_in[5];
    const float* Wi_gru = (const float*)d_in[6];
    const float* Wh_gru = (const float*)d_in[7];
    const float* bi_gru = (const float*)d_in[8];
    const float* bh_gru = (const float*)d_in[9];
    const float* W_ri = (const float*)d_in[10];
    const float* b_ri = (const float*)d_in[11];
    const float* W_rj = (const float*)d_in[12];
    const float* b_rj = (const float*)d_in[13];
    const int* receivers = (const int*)d_in[14];
    const int* senders   = (const int*)d_in[15];
    float* out = (float*)d_out;

    // workspace carve: floats then ints; ~63 MB total
    float* fb      = (float*)d_ws;
    float* hidden0 = fb;                 // 400000
    float* hidA    = fb + 400000;        // 400000
    float* hidB    = fb + 800000;        // 400000
    float* tmp     = fb + 1200000;       // 6400000 (E*16, RECEIVER-order msgs)
    float* efp     = fb + 7600000;       // 6400000 (E*16, sender-order feats)
    int* ib       = (int*)(fb + 14000000);
    int* cnt      = ib;                  // 25024
    int* row_ptr  = ib + 25024;          // 25024
    int* rcnt     = ib + 50048;          // 25024
    int* rrow_ptr = ib + 75072;          // 25024
    int* ipos     = ib + 100096;         // 400000 (edge -> sender-CSR slot)
    int* rp       = ib + 500096;         // 400000 (sender slot -> receiver slot)
    int* rank_s   = ib + 900096;         // 400000
    int* rank_r   = ib + 1300096;        // 400000

    dim3 b256(256);
    int grid_n16 = (N_NODES * 16 + 255) / 256;   // 1563
    int grid_e   = (N_EDGES + 255) / 256;        // 1563
    int grid_e16 = (N_EDGES * 16 + 255) / 256;   // 25000
    int grid_n   = (N_NODES + 255) / 256;        // 98
    int grid_blk = (N_NODES + 15) / 16;          // 1563 (16 senders per block)

    k_init<<<grid_n16, b256, 0, stream>>>(node_features, W_init, b_init,
                                          hidden0, hidA, cnt, rcnt);
    k_rank<<<grid_e, b256, 0, stream>>>(senders, receivers, cnt, rcnt,
                                        rank_s, rank_r);
    k_scan2<<<2, 1024, 0, stream>>>(cnt, row_ptr, rcnt, rrow_ptr, out);
    k_place<<<grid_e, b256, 0, stream>>>(senders, receivers, rank_s, rank_r,
                                         row_ptr, rrow_ptr, ipos, rp);
    k_permute<<<grid_e16, b256, 0, stream>>>(edge_features, ipos, efp);

    float* hin = hidA;
    float* hout = hidB;
    for (int it = 0; it < 3; ++it) {
        k_msg<<<grid_blk, b256, 0, stream>>>(hin, efp, rp,
                                             W_edge, b_edge, row_ptr, tmp);
        k_gru<<<grid_n16, b256, 0, stream>>>(hin, tmp, rrow_ptr,
                                             Wi_gru, Wh_gru, bi_gru, bh_gru, hout);
        float* t = hin; hin = hout; hout = t;
    }

    k_readout<<<grid_n, b256, 0, stream>>>(hin, hidden0, W_ri, b_ri, W_rj, b_rj, out);
}